// Round 9
// baseline (836.942 us; speedup 1.0000x reference)
//
#include <hip/hip_runtime.h>

// Problem constants: B=256, NW=64, WIN=32, FEAT=16, H=64, E=128, NH=4

typedef __attribute__((ext_vector_type(8))) short bf16x8;
typedef __attribute__((ext_vector_type(4))) float f32x4;

__device__ __forceinline__ unsigned short f2bf(float f) {
    union { float f; unsigned int u; } v; v.f = f;
    unsigned int u = v.u;
    return (unsigned short)((u + 0x7FFFu + ((u >> 16) & 1u)) >> 16);
}
__device__ __forceinline__ float dot4_(float4 a, float4 b) {
    return a.x*b.x + a.y*b.y + a.z*b.z + a.w*b.w;
}
__device__ __forceinline__ bf16x8 f2bf8(float4 a, float4 b) {
    bf16x8 o;
    o[0] = (short)f2bf(a.x); o[1] = (short)f2bf(a.y);
    o[2] = (short)f2bf(a.z); o[3] = (short)f2bf(a.w);
    o[4] = (short)f2bf(b.x); o[5] = (short)f2bf(b.y);
    o[6] = (short)f2bf(b.z); o[7] = (short)f2bf(b.w);
    return o;
}
__device__ __forceinline__ float bflo(unsigned u){ union{unsigned u;float f;}v; v.u=u<<16; return v.f; }
__device__ __forceinline__ float bfhi(unsigned u){ union{unsigned u;float f;}v; v.u=u&0xffff0000u; return v.f; }
// Pin a bf16 fragment in VGPRs (defeats loop rematerialization of the load).
#define KEEP(f) { uint4* _p = (uint4*)&(f); \
    asm volatile("" : "+v"(_p->x), "+v"(_p->y), "+v"(_p->z), "+v"(_p->w)); }

// bf16 weight arena layout (ushort element offsets)
#define W_SA_IN   0          // 49152  [384][128]
#define W_SA_OUT  49152      // 16384  [128][128]
#define W_PROJ    65536      // 16384  [128][128]
#define W_IH_F    81920      // 4096   [256][16]
#define W_IH_B    86016      // 4096
#define W_HH_F    90112      // 16384  [256][64]
#define W_HH_B    106496     // 16384
#define W_CA_IN   122880     // 64*49152 = 3145728
#define W_CA_OUT  3268608    // 64*16384 = 1048576
#define NBF_SMALL 122880
#define NBF_FULL  4317184

// ---------------- Kernel 0: weight prep (fp32 -> bf16) ----------------
__global__ __launch_bounds__(256)
void prep_weights(const float* __restrict__ sa_in_w, const float* __restrict__ sa_out_w,
                  const float* __restrict__ proj_w,
                  const float* __restrict__ w_ih_f, const float* __restrict__ w_ih_b,
                  const float* __restrict__ w_hh_f, const float* __restrict__ w_hh_b,
                  const float* __restrict__ ca_in_w, const float* __restrict__ ca_out_w,
                  unsigned short* __restrict__ wbf, int n)
{
    for (int i = blockIdx.x * 256 + threadIdx.x; i < n; i += gridDim.x * 256) {
        float v;
        if (i < W_SA_OUT)       v = sa_in_w[i];
        else if (i < W_PROJ)    v = sa_out_w[i - W_SA_OUT];
        else if (i < W_IH_F)    v = proj_w[i - W_PROJ];
        else if (i < W_IH_B)    v = w_ih_f[i - W_IH_F];
        else if (i < W_HH_F)    v = w_ih_b[i - W_IH_B];
        else if (i < W_HH_B)    v = w_hh_f[i - W_HH_F];
        else if (i < W_CA_IN)   v = w_hh_b[i - W_HH_B];
        else if (i < W_CA_OUT)  v = ca_in_w[i - W_CA_IN];
        else                    v = ca_out_w[i - W_CA_OUT];
        wbf[i] = f2bf(v);
    }
}

// ---------------- Kernel 0b: W2 = proj_w @ sa_out_w, b2 (linear-phase fold) --
__global__ __launch_bounds__(128)
void prep_w2(const float* __restrict__ sa_out_w, const float* __restrict__ sa_out_b,
             const float* __restrict__ proj_w, const float* __restrict__ proj_b,
             unsigned short* __restrict__ w2bf, float* __restrict__ b2f)
{
    __shared__ float pw[128];
    const int e = blockIdx.x, j = threadIdx.x;
    pw[j] = proj_w[e * 128 + j];
    __syncthreads();
    float acc = 0.f;
    #pragma unroll 8
    for (int k = 0; k < 128; ++k) acc += pw[k] * sa_out_w[k * 128 + j];
    w2bf[e * 128 + j] = f2bf(acc);
    if (j == 0) {
        float b = proj_b[e];
        for (int k = 0; k < 128; ++k) b += pw[k] * sa_out_b[k];
        b2f[e] = b;
    }
}

// ---------------- Kernel A: batched MFMA BiLSTM ----------------
#define HB 0            // hbuf[2 buf][2 dir][32 win][72] shorts = 9216
#define XS 9216         // x bf16 [32 win][520]
#define LSTM_SM 25856

__global__ __launch_bounds__(512)
void lstm_kernel(const float* __restrict__ x,
    const float* __restrict__ b_ih_f, const float* __restrict__ b_hh_f,
    const float* __restrict__ b_ih_b, const float* __restrict__ b_hh_b,
    const unsigned short* __restrict__ wbf,
    unsigned short* __restrict__ lo, int win0)
{
    __shared__ __align__(16) unsigned short sm[LSTM_SM];
    const int tid = threadIdx.x;
    const int gbase = win0 + blockIdx.x * 32;
    const int bb = gbase >> 6;
    const int wi0 = gbase & 63;

    for (int i = tid; i < 9216; i += 512) sm[HB + i] = 0;
    #pragma unroll
    for (int i = 0; i < 2; ++i) {
        const int p = tid + i * 512;
        const int win = p >> 5, t = p & 31;
        const float4* src = (const float4*)(x + ((size_t)bb * 2048 + (wi0 + win) * 32 + t) * 16);
        const float4 v0 = src[0], v1 = src[1], v2 = src[2], v3 = src[3];
        *(bf16x8*)&sm[XS + win * 520 + t * 16]     = f2bf8(v0, v1);
        *(bf16x8*)&sm[XS + win * 520 + t * 16 + 8] = f2bf8(v2, v3);
    }
    __syncthreads();

    const int w = tid >> 6, lane = tid & 63;
    const int dir = w >> 2, wd = w & 3;
    const int quad = lane >> 4, n16 = lane & 15;
    const bf16x8 zf = {};

    const unsigned short* whh = wbf + (dir ? W_HH_B : W_HH_F);
    const unsigned short* wih = wbf + (dir ? W_IH_B : W_IH_F);
    const float* bi = dir ? b_ih_b : b_ih_f;
    const float* bh = dir ? b_hh_b : b_hh_f;

    bf16x8 wf[4][2], xf[4];
    float bias[4];
    #pragma unroll
    for (int j = 0; j < 4; ++j) {
        const int g = 64 * j + wd * 16 + n16;
        wf[j][0] = *(const bf16x8*)(whh + g * 64 + quad * 8);
        wf[j][1] = *(const bf16x8*)(whh + g * 64 + 32 + quad * 8);
        KEEP(wf[j][0]); KEEP(wf[j][1]);
        xf[j] = (quad < 2) ? *(const bf16x8*)(wih + g * 16 + quad * 8) : zf;
        KEEP(xf[j]);
        bias[j] = bi[g] + bh[g];
    }
    float c[2][4] = {};
    const size_t loB = (size_t)blockIdx.x * 32;

    for (int s = 0; s < 32; ++s) {
        const int t = dir ? (31 - s) : s;
        const int cur = s & 1, nxt = cur ^ 1;
        #pragma unroll
        for (int mt = 0; mt < 2; ++mt) {
            const int hb = HB + ((cur * 2 + dir) * 32 + mt * 16 + n16) * 72;
            const bf16x8 ah0 = *(const bf16x8*)&sm[hb + quad * 8];
            const bf16x8 ah1 = *(const bf16x8*)&sm[hb + 32 + quad * 8];
            const bf16x8 ax = (quad < 2)
                ? *(const bf16x8*)&sm[XS + (mt * 16 + n16) * 520 + t * 16 + quad * 8] : zf;
            f32x4 ga[4];
            #pragma unroll
            for (int j = 0; j < 4; ++j) {
                f32x4 acc = {bias[j], bias[j], bias[j], bias[j]};
                acc = __builtin_amdgcn_mfma_f32_16x16x32_bf16(ah0, wf[j][0], acc, 0, 0, 0);
                acc = __builtin_amdgcn_mfma_f32_16x16x32_bf16(ah1, wf[j][1], acc, 0, 0, 0);
                acc = __builtin_amdgcn_mfma_f32_16x16x32_bf16(ax,  xf[j],   acc, 0, 0, 0);
                ga[j] = acc;
            }
            #pragma unroll
            for (int r = 0; r < 4; ++r) {
                const float iv = 1.f / (1.f + __expf(-ga[0][r]));
                const float fv = 1.f / (1.f + __expf(-ga[1][r]));
                const float gv = 2.f / (1.f + __expf(-2.f * ga[2][r])) - 1.f;
                const float ov = 1.f / (1.f + __expf(-ga[3][r]));
                c[mt][r] = fv * c[mt][r] + iv * gv;
                const float hv = ov * (2.f / (1.f + __expf(-2.f * c[mt][r])) - 1.f);
                sm[HB + ((nxt * 2 + dir) * 32 + mt * 16 + quad * 4 + r) * 72 + wd * 16 + n16]
                    = f2bf(hv);
            }
        }
        __syncthreads();
        {
            const int win = tid >> 4, part = tid & 15;
            const int d2 = part >> 3, u0 = (part & 7) * 8;
            const int t2 = d2 ? (31 - s) : s;
            const uint4 hv = *(const uint4*)&sm[HB + ((nxt * 2 + d2) * 32 + win) * 72 + u0];
            *(uint4*)(lo + ((loB + win) * 32 + t2) * 128 + d2 * 64 + u0) = hv;
        }
    }
}

// ---------------- Kernel B: per-window attention (MFMA, W2-folded) ----------
#define LO16 0        // lo[32][136]        (later osum[2][128] fp32)
#define Q16  4352     // q[32][136]         (later P, unnormalized)
#define K16  8704     // k[32][136]
#define VT16 13056    // vT[128][40]
#define SM16_TOTAL 18176

__global__ __launch_bounds__(512)
void attn_kernel(const unsigned short* __restrict__ wbf,
    const float* __restrict__ sa_in_b,
    const unsigned short* __restrict__ w2bf, const float* __restrict__ b2f,
    const unsigned short* __restrict__ lo,
    float* __restrict__ pooled, int win0)
{
    __shared__ __align__(16) unsigned short sm16[SM16_TOTAL];
    const int tid = threadIdx.x;

    // stage lo tile
    {
        const uint4 v = *(const uint4*)(lo + (size_t)blockIdx.x * 4096 + tid * 8);
        const int t = tid >> 4, e0 = (tid & 15) * 8;
        *(uint4*)&sm16[LO16 + t * 136 + e0] = v;
    }
    __syncthreads();   // (1)

    const int w    = tid >> 6;
    const int lane = tid & 63;
    const int quad = lane >> 4;
    const int m16  = lane & 15;
    const unsigned short* wqkv = wbf + W_SA_IN;
    const f32x4 z = {0.f, 0.f, 0.f, 0.f};

    // ---- QKV: wave w owns nt = {w, w+8, w+16} -> i=0 all-q, i=1 all-k,
    //      i=2 all-v: epilogue branch is compile-time uniform per unrolled i ----
    {
        bf16x8 afr[2][4];
        #pragma unroll
        for (int mt = 0; mt < 2; ++mt)
            #pragma unroll
            for (int kk = 0; kk < 4; ++kk)
                afr[mt][kk] = *(const bf16x8*)&sm16[LO16 + (mt*16 + m16)*136 + kk*32 + quad*8];
        #pragma unroll
        for (int i = 0; i < 3; ++i) {
            const int nt = w + i * 8;          // 0..7 q, 8..15 k, 16..23 v
            const int e = nt * 16 + m16;       // 0..383
            bf16x8 bfr[4];
            #pragma unroll
            for (int kk = 0; kk < 4; ++kk)
                bfr[kk] = *(const bf16x8*)(wqkv + (size_t)e*128 + kk*32 + quad*8);
            f32x4 acc0 = z, acc1 = z;
            #pragma unroll
            for (int kk = 0; kk < 4; ++kk) {
                acc0 = __builtin_amdgcn_mfma_f32_16x16x32_bf16(afr[0][kk], bfr[kk], acc0, 0, 0, 0);
                acc1 = __builtin_amdgcn_mfma_f32_16x16x32_bf16(afr[1][kk], bfr[kk], acc1, 0, 0, 0);
            }
            const float bias = sa_in_b[e];
            if (i == 0) {
                #pragma unroll
                for (int r = 0; r < 4; ++r) {
                    const int r0 = quad*4 + r;
                    sm16[Q16 + r0*136 + e]        = f2bf(acc0[r] + bias);
                    sm16[Q16 + (16 + r0)*136 + e] = f2bf(acc1[r] + bias);
                }
            } else if (i == 1) {
                const int ek = e - 128;
                #pragma unroll
                for (int r = 0; r < 4; ++r) {
                    const int r0 = quad*4 + r;
                    sm16[K16 + r0*136 + ek]        = f2bf(acc0[r] + bias);
                    sm16[K16 + (16 + r0)*136 + ek] = f2bf(acc1[r] + bias);
                }
            } else {
                const int ev = e - 256;
                #pragma unroll
                for (int r = 0; r < 4; ++r) {
                    const int r0 = quad*4 + r;
                    sm16[VT16 + ev*40 + r0]      = f2bf(acc0[r] + bias);
                    sm16[VT16 + ev*40 + 16 + r0] = f2bf(acc1[r] + bias);
                }
            }
        }
    }
    __syncthreads();   // (2) q,k,vT visible; lo (LO16) now dead

    // ---- scores + MFMA-softmax + P.V + t-sum of O (never materialize O) ----
    {
        const int h  = w >> 1;
        const int mt = w & 1;
        const bf16x8 aq  = *(const bf16x8*)&sm16[Q16 + (mt*16 + m16)*136 + h*32 + quad*8];
        const bf16x8 bk0 = *(const bf16x8*)&sm16[K16 + (m16)*136      + h*32 + quad*8];
        const bf16x8 bk1 = *(const bf16x8*)&sm16[K16 + (16 + m16)*136 + h*32 + quad*8];
        f32x4 s0 = __builtin_amdgcn_mfma_f32_16x16x32_bf16(aq, bk0, z, 0, 0, 0);
        f32x4 s1 = __builtin_amdgcn_mfma_f32_16x16x32_bf16(aq, bk1, z, 0, 0, 0);
        const float scale = 0.17677669529663687f;   // 1/sqrt(32)
        #pragma unroll
        for (int r = 0; r < 4; ++r) {
            const int rowt = mt*16 + quad*4 + r;
            sm16[Q16 + rowt*136 + h*32 + m16]      = f2bf(__expf(s0[r] * scale));
            sm16[Q16 + rowt*136 + h*32 + 16 + m16] = f2bf(__expf(s1[r] * scale));
        }
        const bf16x8 ap  = *(const bf16x8*)&sm16[Q16 + (mt*16 + m16)*136 + h*32 + quad*8];
        bf16x8 ones;
        #pragma unroll
        for (int j = 0; j < 8; ++j) ones[j] = (short)0x3F80;   // bf16 1.0
        const f32x4 sums = __builtin_amdgcn_mfma_f32_16x16x32_bf16(ap, ones, z, 0, 0, 0);
        const bf16x8 bv0 = *(const bf16x8*)&sm16[VT16 + (h*32 + m16)*40      + quad*8];
        const bf16x8 bv1 = *(const bf16x8*)&sm16[VT16 + (h*32 + 16 + m16)*40 + quad*8];
        f32x4 o0 = __builtin_amdgcn_mfma_f32_16x16x32_bf16(ap, bv0, z, 0, 0, 0);
        f32x4 o1 = __builtin_amdgcn_mfma_f32_16x16x32_bf16(ap, bv1, z, 0, 0, 0);
        float cs0 = 0.f, cs1 = 0.f;
        #pragma unroll
        for (int r = 0; r < 4; ++r) {
            const float inv = 1.f / sums[r];
            cs0 += o0[r] * inv;
            cs1 += o1[r] * inv;
        }
        cs0 += __shfl_xor(cs0, 16, 64); cs0 += __shfl_xor(cs0, 32, 64);
        cs1 += __shfl_xor(cs1, 16, 64); cs1 += __shfl_xor(cs1, 32, 64);
        float* osum = (float*)&sm16[LO16];   // [2 mt][128]
        if (quad == 0) {
            osum[mt*128 + h*32 + m16]      = cs0;
            osum[mt*128 + h*32 + 16 + m16] = cs1;
        }
    }
    __syncthreads();   // (3) osum visible

    // ---- GEMV: pooled = mean_t(O) @ W2^T + b2  (all 512 threads, f4 reads) ----
    {
        const float* osum = (const float*)&sm16[LO16];
        const int e = tid >> 2, part = tid & 3;
        const int k0 = part * 32;
        float acc = 0.f;
        const unsigned short* wrow = w2bf + e * 128 + k0;
        #pragma unroll
        for (int j = 0; j < 32; j += 8) {
            const float4 a0 = *(const float4*)&osum[k0 + j];
            const float4 a1 = *(const float4*)&osum[k0 + j + 4];
            const float4 b0 = *(const float4*)&osum[128 + k0 + j];
            const float4 b1 = *(const float4*)&osum[128 + k0 + j + 4];
            const uint4 u = *(const uint4*)(wrow + j);
            acc += (a0.x + b0.x) * bflo(u.x);
            acc += (a0.y + b0.y) * bfhi(u.x);
            acc += (a0.z + b0.z) * bflo(u.y);
            acc += (a0.w + b0.w) * bfhi(u.y);
            acc += (a1.x + b1.x) * bflo(u.z);
            acc += (a1.y + b1.y) * bfhi(u.z);
            acc += (a1.z + b1.z) * bflo(u.w);
            acc += (a1.w + b1.w) * bfhi(u.w);
        }
        acc += __shfl_xor(acc, 1, 64);
        acc += __shfl_xor(acc, 2, 64);
        if (part == 0)
            pooled[((size_t)(win0 + blockIdx.x)) * 128 + e] = acc * 0.03125f + b2f[e];
    }
}

// ---------------- Kernel C: cross-attention + LN (MFMA, 16 batch rows/block) --
__global__ __launch_bounds__(256)
void cross_mfma_kernel(const float* __restrict__ pooled,
    const unsigned short* __restrict__ wbf,
    const float* __restrict__ ca_in_b, const float* __restrict__ ca_out_b,
    const float* __restrict__ ln_g, const float* __restrict__ ln_b,
    float* __restrict__ seq)
{
    __shared__ __align__(16) float cenf[16 * 128];
    __shared__ __align__(16) unsigned short cenb[16 * 136];
    __shared__ __align__(16) unsigned short ctxb[64 * 136];
    __shared__ __align__(16) unsigned short qb[16 * 136];
    __shared__ __align__(16) unsigned short kb[64 * 136];
    __shared__ __align__(16) unsigned short ob[16 * 136];
    __shared__ float attr[256];
    __shared__ float att[256];

    const int blk = blockIdx.x;
    const int ci = blk >> 4;
    const int ch = blk & 15;
    const int tid = threadIdx.x;
    const int w = tid >> 6, lane = tid & 63, quad = lane >> 4, n16 = lane & 15;

    const int left  = (ci - 2 > 0) ? ci - 2 : 0;
    const int right = (ci + 3 < 64) ? ci + 3 : 64;
    const int nc = right - left - 1;

    {
        const int b = tid >> 4, e0 = (tid & 15) * 8;
        const float4* src = (const float4*)(pooled + ((size_t)(ch*16 + b)*64 + ci)*128 + e0);
        const float4 v0 = src[0], v1 = src[1];
        *(float4*)&cenf[b*128 + e0]     = v0;
        *(float4*)&cenf[b*128 + e0 + 4] = v1;
        *(bf16x8*)&cenb[b*136 + e0] = f2bf8(v0, v1);
        for (int n2 = 0; n2 < nc; ++n2) {
            int idx = left + n2; if (idx >= ci) idx++;
            const float4* s2 = (const float4*)(pooled + ((size_t)(ch*16 + b)*64 + idx)*128 + e0);
            *(bf16x8*)&ctxb[(n2*16 + b)*136 + e0] = f2bf8(s2[0], s2[1]);
        }
    }
    __syncthreads();

    const unsigned short* wi = wbf + W_CA_IN + (size_t)ci * 49152;

    #pragma unroll
    for (int i = 0; i < 2; ++i) {
        const int nt = w + i * 4;
        const int e = nt * 16 + n16;
        {
            const float bq = ca_in_b[ci*384 + e];
            f32x4 acc = {bq, bq, bq, bq};
            #pragma unroll
            for (int kk = 0; kk < 4; ++kk) {
                const bf16x8 a = *(const bf16x8*)&cenb[n16*136 + kk*32 + quad*8];
                const bf16x8 bfr = *(const bf16x8*)(wi + (size_t)e*128 + kk*32 + quad*8);
                acc = __builtin_amdgcn_mfma_f32_16x16x32_bf16(a, bfr, acc, 0, 0, 0);
            }
            #pragma unroll
            for (int r = 0; r < 4; ++r) qb[(quad*4 + r)*136 + e] = f2bf(acc[r]);
        }
        {
            bf16x8 bk[4];
            #pragma unroll
            for (int kk = 0; kk < 4; ++kk)
                bk[kk] = *(const bf16x8*)(wi + (size_t)(128 + e)*128 + kk*32 + quad*8);
            const float bkb = ca_in_b[ci*384 + 128 + e];
            for (int mt = 0; mt < nc; ++mt) {
                f32x4 acc = {bkb, bkb, bkb, bkb};
                #pragma unroll
                for (int kk = 0; kk < 4; ++kk) {
                    const bf16x8 a = *(const bf16x8*)&ctxb[(mt*16 + n16)*136 + kk*32 + quad*8];
                    acc = __builtin_amdgcn_mfma_f32_16x16x32_bf16(a, bk[kk], acc, 0, 0, 0);
                }
                #pragma unroll
                for (int r = 0; r < 4; ++r) kb[(mt*16 + quad*4 + r)*136 + e] = f2bf(acc[r]);
            }
        }
    }
    __syncthreads();

    {
        const int h = w;
        const bf16x8 aq = *(const bf16x8*)&qb[n16*136 + h*32 + quad*8];
        for (int n2 = 0; n2 < nc; ++n2) {
            const bf16x8 bk = *(const bf16x8*)&kb[(n2*16 + n16)*136 + h*32 + quad*8];
            const f32x4 z = {0.f, 0.f, 0.f, 0.f};
            const f32x4 s = __builtin_amdgcn_mfma_f32_16x16x32_bf16(aq, bk, z, 0, 0, 0);
            if ((n16 >> 2) == quad)
                attr[(h*4 + n2)*16 + n16] = s[n16 & 3] * 0.17677669529663687f;
        }
    }
    __syncthreads();

    if (tid < 64) {
        const int b = tid & 15, h = tid >> 4;
        float m = -1e30f;
        for (int n2 = 0; n2 < nc; ++n2) m = fmaxf(m, attr[(h*4 + n2)*16 + b]);
        float e2[4]; float sum = 0.f;
        for (int n2 = 0; n2 < nc; ++n2) { e2[n2] = __expf(attr[(h*4 + n2)*16 + b] - m); sum += e2[n2]; }
        const float inv = 1.f / sum;
        for (int n2 = 0; n2 < nc; ++n2) att[b*16 + h*4 + n2] = e2[n2] * inv;
    }
    __syncthreads();

    #pragma unroll
    for (int i = 0; i < 2; ++i) {
        const int nt = w + i * 4;
        const int e = nt * 16 + n16;
        const int he = nt >> 1;
        bf16x8 bv[4];
        #pragma unroll
        for (int kk = 0; kk < 4; ++kk)
            bv[kk] = *(const bf16x8*)(wi + (size_t)(256 + e)*128 + kk*32 + quad*8);
        const float bvb = ca_in_b[ci*384 + 256 + e];
        float accO[4] = {bvb, bvb, bvb, bvb};
        for (int mt = 0; mt < nc; ++mt) {
            f32x4 vv = {0.f, 0.f, 0.f, 0.f};
            #pragma unroll
            for (int kk = 0; kk < 4; ++kk) {
                const bf16x8 a = *(const bf16x8*)&ctxb[(mt*16 + n16)*136 + kk*32 + quad*8];
                vv = __builtin_amdgcn_mfma_f32_16x16x32_bf16(a, bv[kk], vv, 0, 0, 0);
            }
            #pragma unroll
            for (int r = 0; r < 4; ++r)
                accO[r] += att[(quad*4 + r)*16 + he*4 + mt] * vv[r];
        }
        #pragma unroll
        for (int r = 0; r < 4; ++r) ob[(quad*4 + r)*136 + e] = f2bf(accO[r]);
    }
    __syncthreads();

    const unsigned short* wo = wbf + W_CA_OUT + (size_t)ci * 16384;
    float* resf = (float*)ctxb;
    #pragma unroll
    for (int i = 0; i < 2; ++i) {
        const int nt = w + i * 4;
        const int e = nt * 16 + n16;
        const float bo = ca_out_b[ci*128 + e];
        f32x4 acc = {bo, bo, bo, bo};
        #pragma unroll
        for (int kk = 0; kk < 4; ++kk) {
            const bf16x8 a = *(const bf16x8*)&ob[n16*136 + kk*32 + quad*8];
            const bf16x8 bfr = *(const bf16x8*)(wo + (size_t)e*128 + kk*32 + quad*8);
            acc = __builtin_amdgcn_mfma_f32_16x16x32_bf16(a, bfr, acc, 0, 0, 0);
        }
        #pragma unroll
        for (int r = 0; r < 4; ++r) {
            const int b2 = quad*4 + r;
            resf[b2*128 + e] = acc[r] + cenf[b2*128 + e];
        }
    }
    __syncthreads();

    {
        const int b = tid >> 4, i16 = tid & 15;
        const float4 v0 = *(float4*)&resf[b*128 + i16*8];
        const float4 v1 = *(float4*)&resf[b*128 + i16*8 + 4];
        float sum = v0.x+v0.y+v0.z+v0.w + v1.x+v1.y+v1.z+v1.w;
        float sq = v0.x*v0.x+v0.y*v0.y+v0.z*v0.z+v0.w*v0.w
                 + v1.x*v1.x+v1.y*v1.y+v1.z*v1.z+v1.w*v1.w;
        #pragma unroll
        for (int msk = 1; msk < 16; msk <<= 1) {
            sum += __shfl_xor(sum, msk, 64);
            sq  += __shfl_xor(sq, msk, 64);
        }
        const float mean = sum * (1.f / 128.f);
        const float var = sq * (1.f / 128.f) - mean * mean;
        const float rstd = rsqrtf(var + 1e-5f);
        float* dst = seq + ((size_t)(ch*16 + b)*64 + ci)*128 + i16*8;
        const float* gp = ln_g + ci*128 + i16*8;
        const float* bp = ln_b + ci*128 + i16*8;
        float4 o0, o1;
        o0.x = (v0.x-mean)*rstd*gp[0]+bp[0]; o0.y = (v0.y-mean)*rstd*gp[1]+bp[1];
        o0.z = (v0.z-mean)*rstd*gp[2]+bp[2]; o0.w = (v0.w-mean)*rstd*gp[3]+bp[3];
        o1.x = (v1.x-mean)*rstd*gp[4]+bp[4]; o1.y = (v1.y-mean)*rstd*gp[5]+bp[5];
        o1.z = (v1.z-mean)*rstd*gp[6]+bp[6]; o1.w = (v1.w-mean)*rstd*gp[7]+bp[7];
        *(float4*)dst = o0;
        *(float4*)(dst + 4) = o1;
    }
}

// ---------------- Kernel: final MLP head (64 blocks x 4 rows) ----------------
// 4 batch rows per block: each fd1_w float4 is loaded once and used for 4 rows
// -> fd1_w L3 traffic 512 MB -> 128 MB (round-8 post-mortem).
__global__ __launch_bounds__(1024)
void head_kernel(const float* __restrict__ seq,
    const float* __restrict__ fd1_w, const float* __restrict__ fd1_b,
    const float* __restrict__ fd2_w, const float* __restrict__ fd2_b,
    float* __restrict__ out)
{
    const int bb4 = blockIdx.x;     // batch rows 4*bb4 .. 4*bb4+3
    const int tid = threadIdx.x;
    const int j = tid >> 4, part = tid & 15;   // j: unit 0..63, part: 16-way k-split
    __shared__ float4 red[1024];    // 16 KB
    __shared__ float h1[4][64];
    float a0 = 0.f, a1 = 0.f, a2 = 0.f, a3 = 0.f;
    const float4* wr = (const float4*)(fd1_w + (size_t)j * 8192 + part * 512);
    const float4* s0 = (const float4*)(seq + ((size_t)bb4*4 + 0) * 8192 + part * 512);
    const float4* s1 = (const float4*)(seq + ((size_t)bb4*4 + 1) * 8192 + part * 512);
    const float4* s2 = (const float4*)(seq + ((size_t)bb4*4 + 2) * 8192 + part * 512);
    const float4* s3 = (const float4*)(seq + ((size_t)bb4*4 + 3) * 8192 + part * 512);
    #pragma unroll 4
    for (int i = 0; i < 128; ++i) {
        const float4 w4 = wr[i];
        a0 += dot4_(s0[i], w4);
        a1 += dot4_(s1[i], w4);
        a2 += dot4_(s2[i], w4);
        a3 += dot4_(s3[i], w4);
    }
    red[tid] = make_float4(a0, a1, a2, a3);
    __syncthreads();
    if (tid < 64) {
        float t0 = fd1_b[tid], t1 = t0, t2 = t0, t3 = t0;
        #pragma unroll
        for (int p = 0; p < 16; ++p) {
            const float4 v = red[tid * 16 + p];
            t0 += v.x; t1 += v.y; t2 += v.z; t3 += v.w;
        }
        h1[0][tid] = fmaxf(t0, 0.f);
        h1[1][tid] = fmaxf(t1, 0.f);
        h1[2][tid] = fmaxf(t2, 0.f);
        h1[3][tid] = fmaxf(t3, 0.f);
    }
    __syncthreads();
    if (tid < 20) {
        const int r = tid / 5, o = tid % 5;
        float acc2 = fd2_b[o];
        const float* w2 = fd2_w + o * 64;
        #pragma unroll
        for (int k = 0; k < 64; ++k) acc2 += h1[r][k] * w2[k];
        out[(bb4 * 4 + r) * 5 + o] = acc2;
    }
}

// =====================  FALLBACK PATH (round-4, known-good)  =================
__global__ __launch_bounds__(512)
void fused_window_kernel(const float* __restrict__ x,
    const float* __restrict__ w_ih_f, const float* __restrict__ w_hh_f,
    const float* __restrict__ b_ih_f, const float* __restrict__ b_hh_f,
    const float* __restrict__ w_ih_b, const float* __restrict__ w_hh_b,
    const float* __restrict__ b_ih_b, const float* __restrict__ b_hh_b,
    const float* __restrict__ sa_in_b, const float* __restrict__ sa_out_b,
    const float* __restrict__ proj_b,
    const unsigned short* __restrict__ wbf,
    float* __restrict__ pooled)
{
    __shared__ __align__(16) unsigned short sm16[SM16_TOTAL];
    float* xs   = (float*)&sm16[VT16];
    float* hbuf = xs + 512;
    const int tid = threadIdx.x;
    const int blk = blockIdx.x;
    const int bb = blk >> 6, wi2 = blk & 63;
    {
        const float* xsrc = x + ((size_t)bb * 2048 + wi2 * 32) * 16;
        xs[tid & 511] = xsrc[tid];
        if (tid < 256) hbuf[tid] = 0.f;
    }
    __syncthreads();
    {
        const int dir  = tid >> 8;
        const int gg   = tid & 255;
        const int u    = gg >> 2;
        const int gate = gg & 3;
        const int row  = gate * 64 + u;
        const float4* wih_p = (const float4*)((dir ? w_ih_b : w_ih_f) + row * 16);
        const float4* whh_p = (const float4*)((dir ? w_hh_b : w_hh_f) + row * 64);
        float4 wih[4];
        #pragma unroll
        for (int i = 0; i < 4; ++i) wih[i] = wih_p[i];
        float4 whh[16];
        #pragma unroll
        for (int i = 0; i < 16; ++i) whh[i] = whh_p[i];
        const float bias = dir ? (b_ih_b[row] + b_hh_b[row]) : (b_ih_f[row] + b_hh_f[row]);
        const float km  = (gate == 2) ? 2.f : 1.f;
        const float ofs = (gate == 2) ? -1.f : 0.f;
        const int qb2 = (tid & 63) & ~3;
        float c = 0.f;
        for (int step = 0; step < 32; ++step) {
            const int t = dir ? (31 - step) : step;
            const float4* h4 = (const float4*)&hbuf[(step & 1) * 128 + dir * 64];
            const float4* x4 = (const float4*)&xs[t * 16];
            float a0 = bias, a1 = 0.f, a2 = 0.f, a3 = 0.f;
            #pragma unroll
            for (int j = 0; j < 16; j += 4) {
                a0 += dot4_(h4[j], whh[j]);     a1 += dot4_(h4[j+1], whh[j+1]);
                a2 += dot4_(h4[j+2], whh[j+2]); a3 += dot4_(h4[j+3], whh[j+3]);
            }
            a0 += dot4_(x4[0], wih[0]); a1 += dot4_(x4[1], wih[1]);
            a2 += dot4_(x4[2], wih[2]); a3 += dot4_(x4[3], wih[3]);
            const float acc = (a0 + a1) + (a2 + a3);
            const float act = km / (1.f + __expf(-km * acc)) + ofs;
            const float iv = __shfl(act, qb2 + 0, 64);
            const float fv = __shfl(act, qb2 + 1, 64);
            const float gv = __shfl(act, qb2 + 2, 64);
            const float ov = __shfl(act, qb2 + 3, 64);
            c = fv * c + iv * gv;
            const float h = ov * (2.f / (1.f + __expf(-2.f * c)) - 1.f);
            if (gate == 0) {
                hbuf[((step + 1) & 1) * 128 + dir * 64 + u] = h;
                sm16[LO16 + t * 136 + dir * 64 + u] = f2bf(h);
            }
            __syncthreads();
        }
    }
    const int w = tid >> 6, lane = tid & 63, quad = lane >> 4, m16 = lane & 15;
    const unsigned short* wqkv = wbf + W_SA_IN;
    const unsigned short* wout = wbf + W_SA_OUT;
    const unsigned short* wprj = wbf + W_PROJ;
    {
        const int mt = w & 1, ng = w >> 1;
        bf16x8 afr[4];
        #pragma unroll
        for (int kk = 0; kk < 4; ++kk)
            afr[kk] = *(const bf16x8*)&sm16[LO16 + (mt*16 + m16)*136 + kk*32 + quad*8];
        #pragma unroll
        for (int i = 0; i < 6; ++i) {
            const int nt = ng * 6 + i;
            f32x4 acc = {0.f, 0.f, 0.f, 0.f};
            #pragma unroll
            for (int kk = 0; kk < 4; ++kk) {
                const bf16x8 bfr = *(const bf16x8*)(wqkv + (nt*16 + m16)*128 + kk*32 + quad*8);
                acc = __builtin_amdgcn_mfma_f32_16x16x32_bf16(afr[kk], bfr, acc, 0, 0, 0);
            }
            const int e = nt * 16 + m16;
            const float bias = sa_in_b[e];
            #pragma unroll
            for (int r = 0; r < 4; ++r) {
                const int rowt = mt*16 + quad*4 + r;
                const unsigned short hv = f2bf(acc[r] + bias);
                if (e < 128)       sm16[Q16 + rowt*136 + e] = hv;
                else if (e < 256)  sm16[K16 + rowt*136 + (e - 128)] = hv;
                else               sm16[VT16 + (e - 256)*40 + rowt] = hv;
            }
        }
    }
    __syncthreads();
    {
        const int h = w >> 1, mt = w & 1;
        const bf16x8 aq  = *(const bf16x8*)&sm16[Q16 + (mt*16 + m16)*136 + h*32 + quad*8];
        const bf16x8 bk0 = *(const bf16x8*)&sm16[K16 + (m16)*136      + h*32 + quad*8];
        const bf16x8 bk1 = *(const bf16x8*)&sm16[K16 + (16 + m16)*136 + h*32 + quad*8];
        __syncthreads();
        const f32x4 z = {0.f, 0.f, 0.f, 0.f};
        f32x4 s0 = __builtin_amdgcn_mfma_f32_16x16x32_bf16(aq, bk0, z, 0, 0, 0);
        f32x4 s1 = __builtin_amdgcn_mfma_f32_16x16x32_bf16(aq, bk1, z, 0, 0, 0);
        const float scale = 0.17677669529663687f;
        #pragma unroll
        for (int r = 0; r < 4; ++r) {
            float v0 = s0[r] * scale, v1 = s1[r] * scale;
            float mx = fmaxf(v0, v1);
            #pragma unroll
            for (int msk = 1; msk < 16; msk <<= 1) mx = fmaxf(mx, __shfl_xor(mx, msk, 64));
            const float e0 = __expf(v0 - mx), e1 = __expf(v1 - mx);
            float sum = e0 + e1;
            #pragma unroll
            for (int msk = 1; msk < 16; msk <<= 1) sum += __shfl_xor(sum, msk, 64);
            const float inv = 1.f / sum;
            const int rowt = mt*16 + quad*4 + r;
            sm16[Q16 + rowt*136 + h*32 + m16]      = f2bf(e0 * inv);
            sm16[Q16 + rowt*136 + h*32 + 16 + m16] = f2bf(e1 * inv);
        }
        const bf16x8 ap  = *(const bf16x8*)&sm16[Q16 + (mt*16 + m16)*136 + h*32 + quad*8];
        const bf16x8 bv0 = *(const bf16x8*)&sm16[VT16 + (h*32 + m16)*40      + quad*8];
        const bf16x8 bv1 = *(const bf16x8*)&sm16[VT16 + (h*32 + 16 + m16)*40 + quad*8];
        f32x4 o0 = __builtin_amdgcn_mfma_f32_16x16x32_bf16(ap, bv0, z, 0, 0, 0);
        f32x4 o1 = __builtin_amdgcn_mfma_f32_16x16x32_bf16(ap, bv1, z, 0, 0, 0);
        #pragma unroll
        for (int r = 0; r < 4; ++r) {
            const int rowt = mt*16 + quad*4 + r;
            sm16[K16 + rowt*136 + h*32 + m16]      = f2bf(o0[r]);
            sm16[K16 + rowt*136 + h*32 + 16 + m16] = f2bf(o1[r]);
        }
    }
    __syncthreads();
    {
        const int mt = w & 1;
        bf16x8 ao[4];
        #pragma unroll
        for (int kk = 0; kk < 4; ++kk)
            ao[kk] = *(const bf16x8*)&sm16[K16 + (mt*16 + m16)*136 + kk*32 + quad*8];
        #pragma unroll
        for (int i = 0; i < 2; ++i) {
            const int nt = (w >> 1) * 2 + i;
            f32x4 acc = {0.f, 0.f, 0.f, 0.f};
            #pragma unroll
            for (int kk = 0; kk < 4; ++kk) {
                const bf16x8 bfr = *(const bf16x8*)(wout + (nt*16 + m16)*128 + kk*32 + quad*8);
                acc = __builtin_amdgcn_mfma_f32_16x16x32_bf16(ao[kk], bfr, acc, 0, 0, 0);
            }
            const int e = nt * 16 + m16;
            const float bias = sa_out_b[e];
            #pragma unroll
            for (int r = 0; r < 4; ++r)
                sm16[LO16 + (mt*16 + quad*4 + r)*136 + e] = f2bf(acc[r] + bias);
        }
    }
    __syncthreads();
    {
        f32x4 acc0 = {0.f, 0.f, 0.f, 0.f};
        f32x4 acc1 = {0.f, 0.f, 0.f, 0.f};
        #pragma unroll
        for (int kk = 0; kk < 4; ++kk) {
            const bf16x8 a0 = *(const bf16x8*)&sm16[LO16 + (m16)*136      + kk*32 + quad*8];
            const bf16x8 a1 = *(const bf16x8*)&sm16[LO16 + (16 + m16)*136 + kk*32 + quad*8];
            const bf16x8 bfr = *(const bf16x8*)(wprj + (w*16 + m16)*128 + kk*32 + quad*8);
            acc0 = __builtin_amdgcn_mfma_f32_16x16x32_bf16(a0, bfr, acc0, 0, 0, 0);
            acc1 = __builtin_amdgcn_mfma_f32_16x16x32_bf16(a1, bfr, acc1, 0, 0, 0);
        }
        float s = (acc0[0] + acc0[1]) + (acc0[2] + acc0[3])
                + (acc1[0] + acc1[1]) + (acc1[2] + acc1[3]);
        s += __shfl_down(s, 32, 64);
        s += __shfl_down(s, 16, 64);
        if (lane < 16) {
            const int e = w * 16 + lane;
            pooled[(size_t)blk * 128 + e] = s * 0.03125f + proj_b[e];
        }
    }
}

__global__ __launch_bounds__(128)
void cross_attn_kernel(const float* __restrict__ pooled,
    const float* __restrict__ ca_in_w, const float* __restrict__ ca_in_b,
    const float* __restrict__ ca_out_w, const float* __restrict__ ca_out_b,
    const float* __restrict__ ln_g, const float* __restrict__ ln_b,
    float* __restrict__ seq)
{
    const int blk = blockIdx.x;
    const int ci = blk >> 8, bb = blk & 255;
    const int tid = threadIdx.x;
    __shared__ float cen[128], ctx[512], qsh[128], ksh[512], vsh[512], osh[128];
    __shared__ float att2[16], red[2];
    const int left  = (ci - 2 > 0) ? ci - 2 : 0;
    const int right = (ci + 3 < 64) ? ci + 3 : 64;
    const int nc = right - left - 1;
    cen[tid] = pooled[((size_t)bb * 64 + ci) * 128 + tid];
    for (int n2 = 0; n2 < nc; ++n2) {
        int idx = left + n2; if (idx >= ci) idx++;
        ctx[n2 * 128 + tid] = pooled[((size_t)bb * 64 + idx) * 128 + tid];
    }
    __syncthreads();
    const float* Wi = ca_in_w + (size_t)ci * 384 * 128;
    const float* bi = ca_in_b + ci * 384;
    const int e = tid;
    {
        const float4* wr = (const float4*)(Wi + (size_t)e * 128);
        const float4* cr = (const float4*)cen;
        float acc = bi[e];
        #pragma unroll 8
        for (int j = 0; j < 32; ++j) acc += dot4_(cr[j], wr[j]);
        qsh[e] = acc;
    }
    for (int n2 = 0; n2 < nc; ++n2) {
        const float4* xr = (const float4*)&ctx[n2 * 128];
        const float4* wk = (const float4*)(Wi + (size_t)(128 + e) * 128);
        const float4* wv = (const float4*)(Wi + (size_t)(256 + e) * 128);
        float acck = bi[128 + e], accv = bi[256 + e];
        #pragma unroll 8
        for (int j = 0; j < 32; ++j) {
            const float4 a = xr[j];
            acck += dot4_(a, wk[j]); accv += dot4_(a, wv[j]);
        }
        ksh[n2 * 128 + e] = acck; vsh[n2 * 128 + e] = accv;
    }
    __syncthreads();
    if (tid < 4) {
        const int h = tid;
        float s[4]; float m = -1e30f;
        for (int n2 = 0; n2 < nc; ++n2) {
            float acc = 0.f;
            #pragma unroll
            for (int d = 0; d < 32; ++d) acc += qsh[h*32 + d] * ksh[n2*128 + h*32 + d];
            s[n2] = acc * 0.17677669529663687f;
            m = fmaxf(m, s[n2]);
        }
        float ssum = 0.f;
        for (int n2 = 0; n2 < nc; ++n2) { s[n2] = __expf(s[n2] - m); ssum += s[n2]; }
        const float inv = 1.f / ssum;
        for (int n2 = 0; n2 < nc; ++n2) att2[h*4 + n2] = s[n2] * inv;
    }
    __syncthreads();
    {
        const int h = e >> 5;
        float oacc = 0.f;
        for (int n2 = 0; n2 < nc; ++n2) oacc += att2[h*4 + n2] * vsh[n2*128 + e];
        osh[e] = oacc;
    }
    __syncthreads();
    float res;
    {
        const float4* wr = (const float4*)(ca_out_w + (size_t)ci*128*128 + (size_t)e*128);
        const float4* orow = (const float4*)osh;
        float acc = ca_out_b[ci*128 + e];
        #pragma unroll 8
        for (int j = 0; j < 32; ++j) acc += dot4_(orow[j], wr[j]);
        res = acc + cen[e];
    }
    const int lane = tid & 63, wid = tid >> 6;
    float sum = res;
    #pragma unroll
    for (int off = 32; off > 0; off >>= 1) sum += __shfl_down(sum, off, 64);
    if (lane == 0) red[wid] = sum;
    __syncthreads();
    const float mean = (red[0] + red[1]) * (1.f / 128.f);
    const float dv = res - mean;
    __syncthreads();
    float s2 = dv * dv;
    #pragma unroll
    for (int off = 32; off > 0; off >>= 1) s2 += __shfl_down(s2, off, 64);
    if (lane == 0) red[wid] = s2;
    __syncthreads();
    const float var = (red[0] + red[1]) * (1.f / 128.f);
    const float y = dv * rsqrtf(var + 1e-5f) * ln_g[ci*128 + e] + ln_b[ci*128 + e];
    seq[((size_t)bb * 64 + ci) * 128 + e] = y;
}

extern "C" void kernel_launch(void* const* d_in, const int* in_sizes, int n_in,
                              void* d_out, int out_size, void* d_ws, size_t ws_size,
                              hipStream_t stream) {
    const float* x        = (const float*)d_in[0];
    const float* w_ih_f   = (const float*)d_in[1];
    const float* w_hh_f   = (const float*)d_in[2];
    const float* b_ih_f   = (const float*)d_in[3];
    const float* b_hh_f   = (const float*)d_in[4];
    const float* w_ih_b   = (const float*)d_in[5];
    const float* w_hh_b   = (const float*)d_in[6];
    const float* b_ih_b   = (const float*)d_in[7];
    const float* b_hh_b   = (const float*)d_in[8];
    const float* sa_in_w  = (const float*)d_in[9];
    const float* sa_in_b  = (const float*)d_in[10];
    const float* sa_out_w = (const float*)d_in[11];
    const float* sa_out_b = (const float*)d_in[12];
    const float* proj_w   = (const float*)d_in[13];
    const float* proj_b   = (const float*)d_in[14];
    const float* ca_in_w  = (const float*)d_in[15];
    const float* ca_in_b  = (const float*)d_in[16];
    const float* ca_out_w = (const float*)d_in[17];
    const float* ca_out_b = (const float*)d_in[18];
    const float* ln_g     = (const float*)d_in[19];
    const float* ln_b     = (const float*)d_in[20];
    const float* fd1_w    = (const float*)d_in[21];
    const float* fd1_b    = (const float*)d_in[22];
    const float* fd2_w    = (const float*)d_in[23];
    const float* fd2_b    = (const float*)d_in[24];

    float* pooled = (float*)d_ws;
    float* seq    = pooled + 2097152;
    float* outp   = (float*)d_out;

    const size_t base = 2ull * 8388608 + 8634368;
    const size_t loFull = 134217728ull;

    if (ws_size >= base + loFull / 4) {
        unsigned short* wbf = (unsigned short*)((char*)d_ws + 16777216);
        unsigned short* lo  = (unsigned short*)((char*)d_ws + base);
        unsigned short* w2bf = (unsigned short*)seq;          // 32 KB (dead by cross)
        float* b2f = (float*)(w2bf + 16384);
        const int npass = (ws_size >= base + loFull) ? 1
                        : (ws_size >= base + loFull / 2) ? 2 : 4;
        prep_weights<<<dim3(2048), dim3(256), 0, stream>>>(
            sa_in_w, sa_out_w, proj_w, w_ih_f, w_ih_b, w_hh_f, w_hh_b,
            ca_in_w, ca_out_w, wbf, NBF_FULL);
        prep_w2<<<dim3(128), dim3(128), 0, stream>>>(
            sa_out_w, sa_out_b, proj_w, proj_b, w2bf, b2f);
        const int chunk = 16384 / npass;
        for (int p = 0; p < npass; ++p) {
            const int win0 = p * chunk;
            lstm_kernel<<<dim3(chunk / 32), dim3(512), 0, stream>>>(
                x, b_ih_f, b_hh_f, b_ih_b, b_hh_b, wbf, lo, win0);
            attn_kernel<<<dim3(chunk), dim3(512), 0, stream>>>(
                wbf, sa_in_b, w2bf, b2f, lo, pooled, win0);
        }
        cross_mfma_kernel<<<dim3(1024), dim3(256), 0, stream>>>(
            pooled, wbf, ca_in_b, ca_out_b, ln_g, ln_b, seq);
    } else {
        unsigned short* wbf = (unsigned short*)seq;
        prep_weights<<<dim3(2048), dim3(256), 0, stream>>>(
            sa_in_w, sa_out_w, proj_w, w_ih_f, w_ih_b, w_hh_f, w_hh_b,
            ca_in_w, ca_out_w, wbf, NBF_SMALL);
        fused_window_kernel<<<dim3(16384), dim3(512), 0, stream>>>(
            x, w_ih_f, w_hh_f, b_ih_f, b_hh_f, w_ih_b, w_hh_b, b_ih_b, b_hh_b,
            sa_in_b, sa_out_b, proj_b, wbf, pooled);
        cross_attn_kernel<<<dim3(16384), dim3(128), 0, stream>>>(
            pooled, ca_in_w, ca_in_b, ca_out_w, ca_out_b, ln_g, ln_b, seq);
    }

    head_kernel<<<dim3(64), dim3(1024), 0, stream>>>(
        seq, fd1_w, fd1_b, fd2_w, fd2_b, outp);
}

// Round 10
// 599.825 us; speedup vs baseline: 1.3953x; 1.3953x over previous
//
#include <hip/hip_runtime.h>

// Problem constants: B=256, NW=64, WIN=32, FEAT=16, H=64, E=128, NH=4

typedef __attribute__((ext_vector_type(8))) short bf16x8;
typedef __attribute__((ext_vector_type(4))) float f32x4;

__device__ __forceinline__ unsigned short f2bf(float f) {
    union { float f; unsigned int u; } v; v.f = f;
    unsigned int u = v.u;
    return (unsigned short)((u + 0x7FFFu + ((u >> 16) & 1u)) >> 16);
}
__device__ __forceinline__ float dot4_(float4 a, float4 b) {
    return a.x*b.x + a.y*b.y + a.z*b.z + a.w*b.w;
}
__device__ __forceinline__ bf16x8 f2bf8(float4 a, float4 b) {
    bf16x8 o;
    o[0] = (short)f2bf(a.x); o[1] = (short)f2bf(a.y);
    o[2] = (short)f2bf(a.z); o[3] = (short)f2bf(a.w);
    o[4] = (short)f2bf(b.x); o[5] = (short)f2bf(b.y);
    o[6] = (short)f2bf(b.z); o[7] = (short)f2bf(b.w);
    return o;
}
__device__ __forceinline__ float bflo(unsigned u){ union{unsigned u;float f;}v; v.u=u<<16; return v.f; }
__device__ __forceinline__ float bfhi(unsigned u){ union{unsigned u;float f;}v; v.u=u&0xffff0000u; return v.f; }
// Pin a bf16 fragment in VGPRs (defeats loop rematerialization of the load).
#define KEEP(f) { uint4* _p = (uint4*)&(f); \
    asm volatile("" : "+v"(_p->x), "+v"(_p->y), "+v"(_p->z), "+v"(_p->w)); }

// bf16 weight arena layout (ushort element offsets)
#define W_SA_IN   0          // 49152  [384][128]
#define W_SA_OUT  49152      // 16384  [128][128]
#define W_PROJ    65536      // 16384  [128][128]
#define W_IH_F    81920      // 4096   [256][16]
#define W_IH_B    86016      // 4096
#define W_HH_F    90112      // 16384  [256][64]
#define W_HH_B    106496     // 16384
#define W_CA_IN   122880     // 64*49152 = 3145728
#define W_CA_OUT  3268608    // 64*16384 = 1048576
#define NBF_SMALL 122880
#define NBF_FULL  4317184

// ---------------- Kernel 0: weight prep (fp32 -> bf16) ----------------
__global__ __launch_bounds__(256)
void prep_weights(const float* __restrict__ sa_in_w, const float* __restrict__ sa_out_w,
                  const float* __restrict__ proj_w,
                  const float* __restrict__ w_ih_f, const float* __restrict__ w_ih_b,
                  const float* __restrict__ w_hh_f, const float* __restrict__ w_hh_b,
                  const float* __restrict__ ca_in_w, const float* __restrict__ ca_out_w,
                  unsigned short* __restrict__ wbf, int n)
{
    for (int i = blockIdx.x * 256 + threadIdx.x; i < n; i += gridDim.x * 256) {
        float v;
        if (i < W_SA_OUT)       v = sa_in_w[i];
        else if (i < W_PROJ)    v = sa_out_w[i - W_SA_OUT];
        else if (i < W_IH_F)    v = proj_w[i - W_PROJ];
        else if (i < W_IH_B)    v = w_ih_f[i - W_IH_F];
        else if (i < W_HH_F)    v = w_ih_b[i - W_IH_B];
        else if (i < W_HH_B)    v = w_hh_f[i - W_HH_F];
        else if (i < W_CA_IN)   v = w_hh_b[i - W_HH_B];
        else if (i < W_CA_OUT)  v = ca_in_w[i - W_CA_IN];
        else                    v = ca_out_w[i - W_CA_OUT];
        wbf[i] = f2bf(v);
    }
}

// ---------------- Kernel 0b: W2 = proj_w @ sa_out_w, b2 (linear-phase fold) --
__global__ __launch_bounds__(128)
void prep_w2(const float* __restrict__ sa_out_w, const float* __restrict__ sa_out_b,
             const float* __restrict__ proj_w, const float* __restrict__ proj_b,
             unsigned short* __restrict__ w2bf, float* __restrict__ b2f)
{
    __shared__ float pw[128];
    const int e = blockIdx.x, j = threadIdx.x;
    pw[j] = proj_w[e * 128 + j];
    __syncthreads();
    float acc = 0.f;
    #pragma unroll 8
    for (int k = 0; k < 128; ++k) acc += pw[k] * sa_out_w[k * 128 + j];
    w2bf[e * 128 + j] = f2bf(acc);
    if (j == 0) {
        float b = proj_b[e];
        for (int k = 0; k < 128; ++k) b += pw[k] * sa_out_b[k];
        b2f[e] = b;
    }
}

// ---------------- Kernel A: batched MFMA BiLSTM ----------------
#define HB 0            // hbuf[2 buf][2 dir][32 win][72] shorts = 9216
#define XS 9216         // x bf16 [32 win][520]
#define LSTM_SM 25856

__global__ __launch_bounds__(512)
void lstm_kernel(const float* __restrict__ x,
    const float* __restrict__ b_ih_f, const float* __restrict__ b_hh_f,
    const float* __restrict__ b_ih_b, const float* __restrict__ b_hh_b,
    const unsigned short* __restrict__ wbf,
    unsigned short* __restrict__ lo, int win0)
{
    __shared__ __align__(16) unsigned short sm[LSTM_SM];
    const int tid = threadIdx.x;
    const int gbase = win0 + blockIdx.x * 32;
    const int bb = gbase >> 6;
    const int wi0 = gbase & 63;

    for (int i = tid; i < 9216; i += 512) sm[HB + i] = 0;
    #pragma unroll
    for (int i = 0; i < 2; ++i) {
        const int p = tid + i * 512;
        const int win = p >> 5, t = p & 31;
        const float4* src = (const float4*)(x + ((size_t)bb * 2048 + (wi0 + win) * 32 + t) * 16);
        const float4 v0 = src[0], v1 = src[1], v2 = src[2], v3 = src[3];
        *(bf16x8*)&sm[XS + win * 520 + t * 16]     = f2bf8(v0, v1);
        *(bf16x8*)&sm[XS + win * 520 + t * 16 + 8] = f2bf8(v2, v3);
    }
    __syncthreads();

    const int w = tid >> 6, lane = tid & 63;
    const int dir = w >> 2, wd = w & 3;
    const int quad = lane >> 4, n16 = lane & 15;
    const bf16x8 zf = {};

    const unsigned short* whh = wbf + (dir ? W_HH_B : W_HH_F);
    const unsigned short* wih = wbf + (dir ? W_IH_B : W_IH_F);
    const float* bi = dir ? b_ih_b : b_ih_f;
    const float* bh = dir ? b_hh_b : b_hh_f;

    bf16x8 wf[4][2], xf[4];
    float bias[4];
    #pragma unroll
    for (int j = 0; j < 4; ++j) {
        const int g = 64 * j + wd * 16 + n16;
        wf[j][0] = *(const bf16x8*)(whh + g * 64 + quad * 8);
        wf[j][1] = *(const bf16x8*)(whh + g * 64 + 32 + quad * 8);
        KEEP(wf[j][0]); KEEP(wf[j][1]);
        xf[j] = (quad < 2) ? *(const bf16x8*)(wih + g * 16 + quad * 8) : zf;
        KEEP(xf[j]);
        bias[j] = bi[g] + bh[g];
    }
    float c[2][4] = {};
    const size_t loB = (size_t)blockIdx.x * 32;

    for (int s = 0; s < 32; ++s) {
        const int t = dir ? (31 - s) : s;
        const int cur = s & 1, nxt = cur ^ 1;
        #pragma unroll
        for (int mt = 0; mt < 2; ++mt) {
            const int hb = HB + ((cur * 2 + dir) * 32 + mt * 16 + n16) * 72;
            const bf16x8 ah0 = *(const bf16x8*)&sm[hb + quad * 8];
            const bf16x8 ah1 = *(const bf16x8*)&sm[hb + 32 + quad * 8];
            const bf16x8 ax = (quad < 2)
                ? *(const bf16x8*)&sm[XS + (mt * 16 + n16) * 520 + t * 16 + quad * 8] : zf;
            f32x4 ga[4];
            #pragma unroll
            for (int j = 0; j < 4; ++j) {
                f32x4 acc = {bias[j], bias[j], bias[j], bias[j]};
                acc = __builtin_amdgcn_mfma_f32_16x16x32_bf16(ah0, wf[j][0], acc, 0, 0, 0);
                acc = __builtin_amdgcn_mfma_f32_16x16x32_bf16(ah1, wf[j][1], acc, 0, 0, 0);
                acc = __builtin_amdgcn_mfma_f32_16x16x32_bf16(ax,  xf[j],   acc, 0, 0, 0);
                ga[j] = acc;
            }
            #pragma unroll
            for (int r = 0; r < 4; ++r) {
                const float iv = 1.f / (1.f + __expf(-ga[0][r]));
                const float fv = 1.f / (1.f + __expf(-ga[1][r]));
                const float gv = 2.f / (1.f + __expf(-2.f * ga[2][r])) - 1.f;
                const float ov = 1.f / (1.f + __expf(-ga[3][r]));
                c[mt][r] = fv * c[mt][r] + iv * gv;
                const float hv = ov * (2.f / (1.f + __expf(-2.f * c[mt][r])) - 1.f);
                sm[HB + ((nxt * 2 + dir) * 32 + mt * 16 + quad * 4 + r) * 72 + wd * 16 + n16]
                    = f2bf(hv);
            }
        }
        __syncthreads();
        {
            const int win = tid >> 4, part = tid & 15;
            const int d2 = part >> 3, u0 = (part & 7) * 8;
            const int t2 = d2 ? (31 - s) : s;
            const uint4 hv = *(const uint4*)&sm[HB + ((nxt * 2 + d2) * 32 + win) * 72 + u0];
            *(uint4*)(lo + ((loB + win) * 32 + t2) * 128 + d2 * 64 + u0) = hv;
        }
    }
}

// ---------------- Kernel B: per-window attention (MFMA, W2-folded) ----------
#define LO16 0        // lo[32][136]        (later osum[2][128] fp32)
#define Q16  4352     // q[32][136]         (later P, unnormalized)
#define K16  8704     // k[32][136]
#define VT16 13056    // vT[128][40]
#define SM16_TOTAL 18176

__global__ __launch_bounds__(512)
void attn_kernel(const unsigned short* __restrict__ wbf,
    const float* __restrict__ sa_in_b,
    const unsigned short* __restrict__ w2bf, const float* __restrict__ b2f,
    const unsigned short* __restrict__ lo,
    float* __restrict__ pooled, int win0)
{
    __shared__ __align__(16) unsigned short sm16[SM16_TOTAL];
    const int tid = threadIdx.x;

    // stage lo tile
    {
        const uint4 v = *(const uint4*)(lo + (size_t)blockIdx.x * 4096 + tid * 8);
        const int t = tid >> 4, e0 = (tid & 15) * 8;
        *(uint4*)&sm16[LO16 + t * 136 + e0] = v;
    }
    __syncthreads();   // (1)

    const int w    = tid >> 6;
    const int lane = tid & 63;
    const int quad = lane >> 4;
    const int m16  = lane & 15;
    const unsigned short* wqkv = wbf + W_SA_IN;
    const f32x4 z = {0.f, 0.f, 0.f, 0.f};

    // ---- QKV: wave w owns nt = {w, w+8, w+16} -> i=0 all-q, i=1 all-k,
    //      i=2 all-v: epilogue branch is compile-time uniform per unrolled i ----
    {
        bf16x8 afr[2][4];
        #pragma unroll
        for (int mt = 0; mt < 2; ++mt)
            #pragma unroll
            for (int kk = 0; kk < 4; ++kk)
                afr[mt][kk] = *(const bf16x8*)&sm16[LO16 + (mt*16 + m16)*136 + kk*32 + quad*8];
        #pragma unroll
        for (int i = 0; i < 3; ++i) {
            const int nt = w + i * 8;          // 0..7 q, 8..15 k, 16..23 v
            const int e = nt * 16 + m16;       // 0..383
            bf16x8 bfr[4];
            #pragma unroll
            for (int kk = 0; kk < 4; ++kk)
                bfr[kk] = *(const bf16x8*)(wqkv + (size_t)e*128 + kk*32 + quad*8);
            f32x4 acc0 = z, acc1 = z;
            #pragma unroll
            for (int kk = 0; kk < 4; ++kk) {
                acc0 = __builtin_amdgcn_mfma_f32_16x16x32_bf16(afr[0][kk], bfr[kk], acc0, 0, 0, 0);
                acc1 = __builtin_amdgcn_mfma_f32_16x16x32_bf16(afr[1][kk], bfr[kk], acc1, 0, 0, 0);
            }
            const float bias = sa_in_b[e];
            if (i == 0) {
                #pragma unroll
                for (int r = 0; r < 4; ++r) {
                    const int r0 = quad*4 + r;
                    sm16[Q16 + r0*136 + e]        = f2bf(acc0[r] + bias);
                    sm16[Q16 + (16 + r0)*136 + e] = f2bf(acc1[r] + bias);
                }
            } else if (i == 1) {
                const int ek = e - 128;
                #pragma unroll
                for (int r = 0; r < 4; ++r) {
                    const int r0 = quad*4 + r;
                    sm16[K16 + r0*136 + ek]        = f2bf(acc0[r] + bias);
                    sm16[K16 + (16 + r0)*136 + ek] = f2bf(acc1[r] + bias);
                }
            } else {
                const int ev = e - 256;
                #pragma unroll
                for (int r = 0; r < 4; ++r) {
                    const int r0 = quad*4 + r;
                    sm16[VT16 + ev*40 + r0]      = f2bf(acc0[r] + bias);
                    sm16[VT16 + ev*40 + 16 + r0] = f2bf(acc1[r] + bias);
                }
            }
        }
    }
    __syncthreads();   // (2) q,k,vT visible; lo (LO16) now dead

    // ---- scores + MFMA-softmax + P.V + t-sum of O (never materialize O) ----
    {
        const int h  = w >> 1;
        const int mt = w & 1;
        const bf16x8 aq  = *(const bf16x8*)&sm16[Q16 + (mt*16 + m16)*136 + h*32 + quad*8];
        const bf16x8 bk0 = *(const bf16x8*)&sm16[K16 + (m16)*136      + h*32 + quad*8];
        const bf16x8 bk1 = *(const bf16x8*)&sm16[K16 + (16 + m16)*136 + h*32 + quad*8];
        f32x4 s0 = __builtin_amdgcn_mfma_f32_16x16x32_bf16(aq, bk0, z, 0, 0, 0);
        f32x4 s1 = __builtin_amdgcn_mfma_f32_16x16x32_bf16(aq, bk1, z, 0, 0, 0);
        const float scale = 0.17677669529663687f;   // 1/sqrt(32)
        #pragma unroll
        for (int r = 0; r < 4; ++r) {
            const int rowt = mt*16 + quad*4 + r;
            sm16[Q16 + rowt*136 + h*32 + m16]      = f2bf(__expf(s0[r] * scale));
            sm16[Q16 + rowt*136 + h*32 + 16 + m16] = f2bf(__expf(s1[r] * scale));
        }
        const bf16x8 ap  = *(const bf16x8*)&sm16[Q16 + (mt*16 + m16)*136 + h*32 + quad*8];
        bf16x8 ones;
        #pragma unroll
        for (int j = 0; j < 8; ++j) ones[j] = (short)0x3F80;   // bf16 1.0
        const f32x4 sums = __builtin_amdgcn_mfma_f32_16x16x32_bf16(ap, ones, z, 0, 0, 0);
        const bf16x8 bv0 = *(const bf16x8*)&sm16[VT16 + (h*32 + m16)*40      + quad*8];
        const bf16x8 bv1 = *(const bf16x8*)&sm16[VT16 + (h*32 + 16 + m16)*40 + quad*8];
        f32x4 o0 = __builtin_amdgcn_mfma_f32_16x16x32_bf16(ap, bv0, z, 0, 0, 0);
        f32x4 o1 = __builtin_amdgcn_mfma_f32_16x16x32_bf16(ap, bv1, z, 0, 0, 0);
        float cs0 = 0.f, cs1 = 0.f;
        #pragma unroll
        for (int r = 0; r < 4; ++r) {
            const float inv = 1.f / sums[r];
            cs0 += o0[r] * inv;
            cs1 += o1[r] * inv;
        }
        cs0 += __shfl_xor(cs0, 16, 64); cs0 += __shfl_xor(cs0, 32, 64);
        cs1 += __shfl_xor(cs1, 16, 64); cs1 += __shfl_xor(cs1, 32, 64);
        float* osum = (float*)&sm16[LO16];   // [2 mt][128]
        if (quad == 0) {
            osum[mt*128 + h*32 + m16]      = cs0;
            osum[mt*128 + h*32 + 16 + m16] = cs1;
        }
    }
    __syncthreads();   // (3) osum visible

    // ---- GEMV: pooled = mean_t(O) @ W2^T + b2  (all 512 threads, f4 reads) ----
    {
        const float* osum = (const float*)&sm16[LO16];
        const int e = tid >> 2, part = tid & 3;
        const int k0 = part * 32;
        float acc = 0.f;
        const unsigned short* wrow = w2bf + e * 128 + k0;
        #pragma unroll
        for (int j = 0; j < 32; j += 8) {
            const float4 a0 = *(const float4*)&osum[k0 + j];
            const float4 a1 = *(const float4*)&osum[k0 + j + 4];
            const float4 b0 = *(const float4*)&osum[128 + k0 + j];
            const float4 b1 = *(const float4*)&osum[128 + k0 + j + 4];
            const uint4 u = *(const uint4*)(wrow + j);
            acc += (a0.x + b0.x) * bflo(u.x);
            acc += (a0.y + b0.y) * bfhi(u.x);
            acc += (a0.z + b0.z) * bflo(u.y);
            acc += (a0.w + b0.w) * bfhi(u.y);
            acc += (a1.x + b1.x) * bflo(u.z);
            acc += (a1.y + b1.y) * bfhi(u.z);
            acc += (a1.z + b1.z) * bflo(u.w);
            acc += (a1.w + b1.w) * bfhi(u.w);
        }
        acc += __shfl_xor(acc, 1, 64);
        acc += __shfl_xor(acc, 2, 64);
        if (part == 0)
            pooled[((size_t)(win0 + blockIdx.x)) * 128 + e] = acc * 0.03125f + b2f[e];
    }
}

// ---------------- Kernel C: cross-attention + LN (MFMA, 16 batch rows/block) --
__global__ __launch_bounds__(256)
void cross_mfma_kernel(const float* __restrict__ pooled,
    const unsigned short* __restrict__ wbf,
    const float* __restrict__ ca_in_b, const float* __restrict__ ca_out_b,
    const float* __restrict__ ln_g, const float* __restrict__ ln_b,
    float* __restrict__ seq)
{
    __shared__ __align__(16) float cenf[16 * 128];
    __shared__ __align__(16) unsigned short cenb[16 * 136];
    __shared__ __align__(16) unsigned short ctxb[64 * 136];
    __shared__ __align__(16) unsigned short qb[16 * 136];
    __shared__ __align__(16) unsigned short kb[64 * 136];
    __shared__ __align__(16) unsigned short ob[16 * 136];
    __shared__ float attr[256];
    __shared__ float att[256];

    const int blk = blockIdx.x;
    const int ci = blk >> 4;
    const int ch = blk & 15;
    const int tid = threadIdx.x;
    const int w = tid >> 6, lane = tid & 63, quad = lane >> 4, n16 = lane & 15;

    const int left  = (ci - 2 > 0) ? ci - 2 : 0;
    const int right = (ci + 3 < 64) ? ci + 3 : 64;
    const int nc = right - left - 1;

    {
        const int b = tid >> 4, e0 = (tid & 15) * 8;
        const float4* src = (const float4*)(pooled + ((size_t)(ch*16 + b)*64 + ci)*128 + e0);
        const float4 v0 = src[0], v1 = src[1];
        *(float4*)&cenf[b*128 + e0]     = v0;
        *(float4*)&cenf[b*128 + e0 + 4] = v1;
        *(bf16x8*)&cenb[b*136 + e0] = f2bf8(v0, v1);
        for (int n2 = 0; n2 < nc; ++n2) {
            int idx = left + n2; if (idx >= ci) idx++;
            const float4* s2 = (const float4*)(pooled + ((size_t)(ch*16 + b)*64 + idx)*128 + e0);
            *(bf16x8*)&ctxb[(n2*16 + b)*136 + e0] = f2bf8(s2[0], s2[1]);
        }
    }
    __syncthreads();

    const unsigned short* wi = wbf + W_CA_IN + (size_t)ci * 49152;

    #pragma unroll
    for (int i = 0; i < 2; ++i) {
        const int nt = w + i * 4;
        const int e = nt * 16 + n16;
        {
            const float bq = ca_in_b[ci*384 + e];
            f32x4 acc = {bq, bq, bq, bq};
            #pragma unroll
            for (int kk = 0; kk < 4; ++kk) {
                const bf16x8 a = *(const bf16x8*)&cenb[n16*136 + kk*32 + quad*8];
                const bf16x8 bfr = *(const bf16x8*)(wi + (size_t)e*128 + kk*32 + quad*8);
                acc = __builtin_amdgcn_mfma_f32_16x16x32_bf16(a, bfr, acc, 0, 0, 0);
            }
            #pragma unroll
            for (int r = 0; r < 4; ++r) qb[(quad*4 + r)*136 + e] = f2bf(acc[r]);
        }
        {
            bf16x8 bk[4];
            #pragma unroll
            for (int kk = 0; kk < 4; ++kk)
                bk[kk] = *(const bf16x8*)(wi + (size_t)(128 + e)*128 + kk*32 + quad*8);
            const float bkb = ca_in_b[ci*384 + 128 + e];
            for (int mt = 0; mt < nc; ++mt) {
                f32x4 acc = {bkb, bkb, bkb, bkb};
                #pragma unroll
                for (int kk = 0; kk < 4; ++kk) {
                    const bf16x8 a = *(const bf16x8*)&ctxb[(mt*16 + n16)*136 + kk*32 + quad*8];
                    acc = __builtin_amdgcn_mfma_f32_16x16x32_bf16(a, bk[kk], acc, 0, 0, 0);
                }
                #pragma unroll
                for (int r = 0; r < 4; ++r) kb[(mt*16 + quad*4 + r)*136 + e] = f2bf(acc[r]);
            }
        }
    }
    __syncthreads();

    {
        const int h = w;
        const bf16x8 aq = *(const bf16x8*)&qb[n16*136 + h*32 + quad*8];
        for (int n2 = 0; n2 < nc; ++n2) {
            const bf16x8 bk = *(const bf16x8*)&kb[(n2*16 + n16)*136 + h*32 + quad*8];
            const f32x4 z = {0.f, 0.f, 0.f, 0.f};
            const f32x4 s = __builtin_amdgcn_mfma_f32_16x16x32_bf16(aq, bk, z, 0, 0, 0);
            if ((n16 >> 2) == quad)
                attr[(h*4 + n2)*16 + n16] = s[n16 & 3] * 0.17677669529663687f;
        }
    }
    __syncthreads();

    if (tid < 64) {
        const int b = tid & 15, h = tid >> 4;
        float m = -1e30f;
        for (int n2 = 0; n2 < nc; ++n2) m = fmaxf(m, attr[(h*4 + n2)*16 + b]);
        float e2[4]; float sum = 0.f;
        for (int n2 = 0; n2 < nc; ++n2) { e2[n2] = __expf(attr[(h*4 + n2)*16 + b] - m); sum += e2[n2]; }
        const float inv = 1.f / sum;
        for (int n2 = 0; n2 < nc; ++n2) att[b*16 + h*4 + n2] = e2[n2] * inv;
    }
    __syncthreads();

    #pragma unroll
    for (int i = 0; i < 2; ++i) {
        const int nt = w + i * 4;
        const int e = nt * 16 + n16;
        const int he = nt >> 1;
        bf16x8 bv[4];
        #pragma unroll
        for (int kk = 0; kk < 4; ++kk)
            bv[kk] = *(const bf16x8*)(wi + (size_t)(256 + e)*128 + kk*32 + quad*8);
        const float bvb = ca_in_b[ci*384 + 256 + e];
        float accO[4] = {bvb, bvb, bvb, bvb};
        for (int mt = 0; mt < nc; ++mt) {
            f32x4 vv = {0.f, 0.f, 0.f, 0.f};
            #pragma unroll
            for (int kk = 0; kk < 4; ++kk) {
                const bf16x8 a = *(const bf16x8*)&ctxb[(mt*16 + n16)*136 + kk*32 + quad*8];
                vv = __builtin_amdgcn_mfma_f32_16x16x32_bf16(a, bv[kk], vv, 0, 0, 0);
            }
            #pragma unroll
            for (int r = 0; r < 4; ++r)
                accO[r] += att[(quad*4 + r)*16 + he*4 + mt] * vv[r];
        }
        #pragma unroll
        for (int r = 0; r < 4; ++r) ob[(quad*4 + r)*136 + e] = f2bf(accO[r]);
    }
    __syncthreads();

    const unsigned short* wo = wbf + W_CA_OUT + (size_t)ci * 16384;
    float* resf = (float*)ctxb;
    #pragma unroll
    for (int i = 0; i < 2; ++i) {
        const int nt = w + i * 4;
        const int e = nt * 16 + n16;
        const float bo = ca_out_b[ci*128 + e];
        f32x4 acc = {bo, bo, bo, bo};
        #pragma unroll
        for (int kk = 0; kk < 4; ++kk) {
            const bf16x8 a = *(const bf16x8*)&ob[n16*136 + kk*32 + quad*8];
            const bf16x8 bfr = *(const bf16x8*)(wo + (size_t)e*128 + kk*32 + quad*8);
            acc = __builtin_amdgcn_mfma_f32_16x16x32_bf16(a, bfr, acc, 0, 0, 0);
        }
        #pragma unroll
        for (int r = 0; r < 4; ++r) {
            const int b2 = quad*4 + r;
            resf[b2*128 + e] = acc[r] + cenf[b2*128 + e];
        }
    }
    __syncthreads();

    {
        const int b = tid >> 4, i16 = tid & 15;
        const float4 v0 = *(float4*)&resf[b*128 + i16*8];
        const float4 v1 = *(float4*)&resf[b*128 + i16*8 + 4];
        float sum = v0.x+v0.y+v0.z+v0.w + v1.x+v1.y+v1.z+v1.w;
        float sq = v0.x*v0.x+v0.y*v0.y+v0.z*v0.z+v0.w*v0.w
                 + v1.x*v1.x+v1.y*v1.y+v1.z*v1.z+v1.w*v1.w;
        #pragma unroll
        for (int msk = 1; msk < 16; msk <<= 1) {
            sum += __shfl_xor(sum, msk, 64);
            sq  += __shfl_xor(sq, msk, 64);
        }
        const float mean = sum * (1.f / 128.f);
        const float var = sq * (1.f / 128.f) - mean * mean;
        const float rstd = rsqrtf(var + 1e-5f);
        float* dst = seq + ((size_t)(ch*16 + b)*64 + ci)*128 + i16*8;
        const float* gp = ln_g + ci*128 + i16*8;
        const float* bp = ln_b + ci*128 + i16*8;
        float4 o0, o1;
        o0.x = (v0.x-mean)*rstd*gp[0]+bp[0]; o0.y = (v0.y-mean)*rstd*gp[1]+bp[1];
        o0.z = (v0.z-mean)*rstd*gp[2]+bp[2]; o0.w = (v0.w-mean)*rstd*gp[3]+bp[3];
        o1.x = (v1.x-mean)*rstd*gp[4]+bp[4]; o1.y = (v1.y-mean)*rstd*gp[5]+bp[5];
        o1.z = (v1.z-mean)*rstd*gp[6]+bp[6]; o1.w = (v1.w-mean)*rstd*gp[7]+bp[7];
        *(float4*)dst = o0;
        *(float4*)(dst + 4) = o1;
    }
}

// ---------------- Head stage 1: partial z = seq @ fd1_w^T, k-split ----------
// grid = 64 rowgroups x 8 k-slices = 512 blocks (round-9 post-mortem: 64 blocks
// starved the GPU at 12% occupancy, 283 us). Keeps 4-row fd1_w reuse.
// part layout: [kq][256 rows][64 units] fp32.
__global__ __launch_bounds__(256)
void head1_kernel(const float* __restrict__ seq, const float* __restrict__ fd1_w,
                  float* __restrict__ part)
{
    const int rg = blockIdx.x & 63;     // rows 4*rg .. 4*rg+3
    const int kq = blockIdx.x >> 6;     // 0..7, k-slice of 1024
    const int tid = threadIdx.x;
    const int j = tid & 63;             // unit
    const int sub = tid >> 6;           // 0..3, 256-k sub-slice
    const int k0 = kq * 1024 + sub * 256;
    __shared__ float4 red[256];
    float a0 = 0.f, a1 = 0.f, a2 = 0.f, a3 = 0.f;
    const float4* wr = (const float4*)(fd1_w + (size_t)j * 8192 + k0);
    const float4* s0 = (const float4*)(seq + ((size_t)rg*4 + 0) * 8192 + k0);
    const float4* s1 = (const float4*)(seq + ((size_t)rg*4 + 1) * 8192 + k0);
    const float4* s2 = (const float4*)(seq + ((size_t)rg*4 + 2) * 8192 + k0);
    const float4* s3 = (const float4*)(seq + ((size_t)rg*4 + 3) * 8192 + k0);
    #pragma unroll 4
    for (int i = 0; i < 64; ++i) {
        const float4 w4 = wr[i];
        a0 += dot4_(s0[i], w4);
        a1 += dot4_(s1[i], w4);
        a2 += dot4_(s2[i], w4);
        a3 += dot4_(s3[i], w4);
    }
    red[tid] = make_float4(a0, a1, a2, a3);
    __syncthreads();
    if (tid < 64) {
        const float4 v0 = red[tid], v1 = red[64 + tid], v2 = red[128 + tid], v3 = red[192 + tid];
        float4 t;
        t.x = v0.x + v1.x + v2.x + v3.x;
        t.y = v0.y + v1.y + v2.y + v3.y;
        t.z = v0.z + v1.z + v2.z + v3.z;
        t.w = v0.w + v1.w + v2.w + v3.w;
        float* pb = part + ((size_t)kq * 256 + rg * 4) * 64 + tid;
        pb[0]   = t.x;
        pb[64]  = t.y;
        pb[128] = t.z;
        pb[192] = t.w;
    }
}

// ---------------- Head stage 2: reduce + ReLU + 5-out GEMV ----------------
__global__ __launch_bounds__(64)
void head2_kernel(const float* __restrict__ part,
    const float* __restrict__ fd1_b,
    const float* __restrict__ fd2_w, const float* __restrict__ fd2_b,
    float* __restrict__ out)
{
    const int row = blockIdx.x;
    const int u = threadIdx.x;
    __shared__ float h1[64];
    float s = fd1_b[u];
    #pragma unroll
    for (int kq = 0; kq < 8; ++kq)
        s += part[((size_t)kq * 256 + row) * 64 + u];
    h1[u] = fmaxf(s, 0.f);
    __syncthreads();
    if (u < 5) {
        float acc = fd2_b[u];
        const float* w2 = fd2_w + u * 64;
        #pragma unroll
        for (int k = 0; k < 64; ++k) acc += h1[k] * w2[k];
        out[row * 5 + u] = acc;
    }
}

// =====================  FALLBACK PATH (round-4, known-good)  =================
__global__ __launch_bounds__(512)
void fused_window_kernel(const float* __restrict__ x,
    const float* __restrict__ w_ih_f, const float* __restrict__ w_hh_f,
    const float* __restrict__ b_ih_f, const float* __restrict__ b_hh_f,
    const float* __restrict__ w_ih_b, const float* __restrict__ w_hh_b,
    const float* __restrict__ b_ih_b, const float* __restrict__ b_hh_b,
    const float* __restrict__ sa_in_b, const float* __restrict__ sa_out_b,
    const float* __restrict__ proj_b,
    const unsigned short* __restrict__ wbf,
    float* __restrict__ pooled)
{
    __shared__ __align__(16) unsigned short sm16[SM16_TOTAL];
    float* xs   = (float*)&sm16[VT16];
    float* hbuf = xs + 512;
    const int tid = threadIdx.x;
    const int blk = blockIdx.x;
    const int bb = blk >> 6, wi2 = blk & 63;
    {
        const float* xsrc = x + ((size_t)bb * 2048 + wi2 * 32) * 16;
        xs[tid & 511] = xsrc[tid];
        if (tid < 256) hbuf[tid] = 0.f;
    }
    __syncthreads();
    {
        const int dir  = tid >> 8;
        const int gg   = tid & 255;
        const int u    = gg >> 2;
        const int gate = gg & 3;
        const int row  = gate * 64 + u;
        const float4* wih_p = (const float4*)((dir ? w_ih_b : w_ih_f) + row * 16);
        const float4* whh_p = (const float4*)((dir ? w_hh_b : w_hh_f) + row * 64);
        float4 wih[4];
        #pragma unroll
        for (int i = 0; i < 4; ++i) wih[i] = wih_p[i];
        float4 whh[16];
        #pragma unroll
        for (int i = 0; i < 16; ++i) whh[i] = whh_p[i];
        const float bias = dir ? (b_ih_b[row] + b_hh_b[row]) : (b_ih_f[row] + b_hh_f[row]);
        const float km  = (gate == 2) ? 2.f : 1.f;
        const float ofs = (gate == 2) ? -1.f : 0.f;
        const int qb2 = (tid & 63) & ~3;
        float c = 0.f;
        for (int step = 0; step < 32; ++step) {
            const int t = dir ? (31 - step) : step;
            const float4* h4 = (const float4*)&hbuf[(step & 1) * 128 + dir * 64];
            const float4* x4 = (const float4*)&xs[t * 16];
            float a0 = bias, a1 = 0.f, a2 = 0.f, a3 = 0.f;
            #pragma unroll
            for (int j = 0; j < 16; j += 4) {
                a0 += dot4_(h4[j], whh[j]);     a1 += dot4_(h4[j+1], whh[j+1]);
                a2 += dot4_(h4[j+2], whh[j+2]); a3 += dot4_(h4[j+3], whh[j+3]);
            }
            a0 += dot4_(x4[0], wih[0]); a1 += dot4_(x4[1], wih[1]);
            a2 += dot4_(x4[2], wih[2]); a3 += dot4_(x4[3], wih[3]);
            const float acc = (a0 + a1) + (a2 + a3);
            const float act = km / (1.f + __expf(-km * acc)) + ofs;
            const float iv = __shfl(act, qb2 + 0, 64);
            const float fv = __shfl(act, qb2 + 1, 64);
            const float gv = __shfl(act, qb2 + 2, 64);
            const float ov = __shfl(act, qb2 + 3, 64);
            c = fv * c + iv * gv;
            const float h = ov * (2.f / (1.f + __expf(-2.f * c)) - 1.f);
            if (gate == 0) {
                hbuf[((step + 1) & 1) * 128 + dir * 64 + u] = h;
                sm16[LO16 + t * 136 + dir * 64 + u] = f2bf(h);
            }
            __syncthreads();
        }
    }
    const int w = tid >> 6, lane = tid & 63, quad = lane >> 4, m16 = lane & 15;
    const unsigned short* wqkv = wbf + W_SA_IN;
    const unsigned short* wout = wbf + W_SA_OUT;
    const unsigned short* wprj = wbf + W_PROJ;
    {
        const int mt = w & 1, ng = w >> 1;
        bf16x8 afr[4];
        #pragma unroll
        for (int kk = 0; kk < 4; ++kk)
            afr[kk] = *(const bf16x8*)&sm16[LO16 + (mt*16 + m16)*136 + kk*32 + quad*8];
        #pragma unroll
        for (int i = 0; i < 6; ++i) {
            const int nt = ng * 6 + i;
            f32x4 acc = {0.f, 0.f, 0.f, 0.f};
            #pragma unroll
            for (int kk = 0; kk < 4; ++kk) {
                const bf16x8 bfr = *(const bf16x8*)(wqkv + (nt*16 + m16)*128 + kk*32 + quad*8);
                acc = __builtin_amdgcn_mfma_f32_16x16x32_bf16(afr[kk], bfr, acc, 0, 0, 0);
            }
            const int e = nt * 16 + m16;
            const float bias = sa_in_b[e];
            #pragma unroll
            for (int r = 0; r < 4; ++r) {
                const int rowt = mt*16 + quad*4 + r;
                const unsigned short hv = f2bf(acc[r] + bias);
                if (e < 128)       sm16[Q16 + rowt*136 + e] = hv;
                else if (e < 256)  sm16[K16 + rowt*136 + (e - 128)] = hv;
                else               sm16[VT16 + (e - 256)*40 + rowt] = hv;
            }
        }
    }
    __syncthreads();
    {
        const int h = w >> 1, mt = w & 1;
        const bf16x8 aq  = *(const bf16x8*)&sm16[Q16 + (mt*16 + m16)*136 + h*32 + quad*8];
        const bf16x8 bk0 = *(const bf16x8*)&sm16[K16 + (m16)*136      + h*32 + quad*8];
        const bf16x8 bk1 = *(const bf16x8*)&sm16[K16 + (16 + m16)*136 + h*32 + quad*8];
        __syncthreads();
        const f32x4 z = {0.f, 0.f, 0.f, 0.f};
        f32x4 s0 = __builtin_amdgcn_mfma_f32_16x16x32_bf16(aq, bk0, z, 0, 0, 0);
        f32x4 s1 = __builtin_amdgcn_mfma_f32_16x16x32_bf16(aq, bk1, z, 0, 0, 0);
        const float scale = 0.17677669529663687f;
        #pragma unroll
        for (int r = 0; r < 4; ++r) {
            float v0 = s0[r] * scale, v1 = s1[r] * scale;
            float mx = fmaxf(v0, v1);
            #pragma unroll
            for (int msk = 1; msk < 16; msk <<= 1) mx = fmaxf(mx, __shfl_xor(mx, msk, 64));
            const float e0 = __expf(v0 - mx), e1 = __expf(v1 - mx);
            float sum = e0 + e1;
            #pragma unroll
            for (int msk = 1; msk < 16; msk <<= 1) sum += __shfl_xor(sum, msk, 64);
            const float inv = 1.f / sum;
            const int rowt = mt*16 + quad*4 + r;
            sm16[Q16 + rowt*136 + h*32 + m16]      = f2bf(e0 * inv);
            sm16[Q16 + rowt*136 + h*32 + 16 + m16] = f2bf(e1 * inv);
        }
        const bf16x8 ap  = *(const bf16x8*)&sm16[Q16 + (mt*16 + m16)*136 + h*32 + quad*8];
        const bf16x8 bv0 = *(const bf16x8*)&sm16[VT16 + (h*32 + m16)*40      + quad*8];
        const bf16x8 bv1 = *(const bf16x8*)&sm16[VT16 + (h*32 + 16 + m16)*40 + quad*8];
        f32x4 o0 = __builtin_amdgcn_mfma_f32_16x16x32_bf16(ap, bv0, z, 0, 0, 0);
        f32x4 o1 = __builtin_amdgcn_mfma_f32_16x16x32_bf16(ap, bv1, z, 0, 0, 0);
        #pragma unroll
        for (int r = 0; r < 4; ++r) {
            const int rowt = mt*16 + quad*4 + r;
            sm16[K16 + rowt*136 + h*32 + m16]      = f2bf(o0[r]);
            sm16[K16 + rowt*136 + h*32 + 16 + m16] = f2bf(o1[r]);
        }
    }
    __syncthreads();
    {
        const int mt = w & 1;
        bf16x8 ao[4];
        #pragma unroll
        for (int kk = 0; kk < 4; ++kk)
            ao[kk] = *(const bf16x8*)&sm16[K16 + (mt*16 + m16)*136 + kk*32 + quad*8];
        #pragma unroll
        for (int i = 0; i < 2; ++i) {
            const int nt = (w >> 1) * 2 + i;
            f32x4 acc = {0.f, 0.f, 0.f, 0.f};
            #pragma unroll
            for (int kk = 0; kk < 4; ++kk) {
                const bf16x8 bfr = *(const bf16x8*)(wout + (nt*16 + m16)*128 + kk*32 + quad*8);
                acc = __builtin_amdgcn_mfma_f32_16x16x32_bf16(ao[kk], bfr, acc, 0, 0, 0);
            }
            const int e = nt * 16 + m16;
            const float bias = sa_out_b[e];
            #pragma unroll
            for (int r = 0; r < 4; ++r)
                sm16[LO16 + (mt*16 + quad*4 + r)*136 + e] = f2bf(acc[r] + bias);
        }
    }
    __syncthreads();
    {
        f32x4 acc0 = {0.f, 0.f, 0.f, 0.f};
        f32x4 acc1 = {0.f, 0.f, 0.f, 0.f};
        #pragma unroll
        for (int kk = 0; kk < 4; ++kk) {
            const bf16x8 a0 = *(const bf16x8*)&sm16[LO16 + (m16)*136      + kk*32 + quad*8];
            const bf16x8 a1 = *(const bf16x8*)&sm16[LO16 + (16 + m16)*136 + kk*32 + quad*8];
            const bf16x8 bfr = *(const bf16x8*)(wprj + (w*16 + m16)*128 + kk*32 + quad*8);
            acc0 = __builtin_amdgcn_mfma_f32_16x16x32_bf16(a0, bfr, acc0, 0, 0, 0);
            acc1 = __builtin_amdgcn_mfma_f32_16x16x32_bf16(a1, bfr, acc1, 0, 0, 0);
        }
        float s = (acc0[0] + acc0[1]) + (acc0[2] + acc0[3])
                + (acc1[0] + acc1[1]) + (acc1[2] + acc1[3]);
        s += __shfl_down(s, 32, 64);
        s += __shfl_down(s, 16, 64);
        if (lane < 16) {
            const int e = w * 16 + lane;
            pooled[(size_t)blk * 128 + e] = s * 0.03125f + proj_b[e];
        }
    }
}

__global__ __launch_bounds__(128)
void cross_attn_kernel(const float* __restrict__ pooled,
    const float* __restrict__ ca_in_w, const float* __restrict__ ca_in_b,
    const float* __restrict__ ca_out_w, const float* __restrict__ ca_out_b,
    const float* __restrict__ ln_g, const float* __restrict__ ln_b,
    float* __restrict__ seq)
{
    const int blk = blockIdx.x;
    const int ci = blk >> 8, bb = blk & 255;
    const int tid = threadIdx.x;
    __shared__ float cen[128], ctx[512], qsh[128], ksh[512], vsh[512], osh[128];
    __shared__ float att2[16], red[2];
    const int left  = (ci - 2 > 0) ? ci - 2 : 0;
    const int right = (ci + 3 < 64) ? ci + 3 : 64;
    const int nc = right - left - 1;
    cen[tid] = pooled[((size_t)bb * 64 + ci) * 128 + tid];
    for (int n2 = 0; n2 < nc; ++n2) {
        int idx = left + n2; if (idx >= ci) idx++;
        ctx[n2 * 128 + tid] = pooled[((size_t)bb * 64 + idx) * 128 + tid];
    }
    __syncthreads();
    const float* Wi = ca_in_w + (size_t)ci * 384 * 128;
    const float* bi = ca_in_b + ci * 384;
    const int e = tid;
    {
        const float4* wr = (const float4*)(Wi + (size_t)e * 128);
        const float4* cr = (const float4*)cen;
        float acc = bi[e];
        #pragma unroll 8
        for (int j = 0; j < 32; ++j) acc += dot4_(cr[j], wr[j]);
        qsh[e] = acc;
    }
    for (int n2 = 0; n2 < nc; ++n2) {
        const float4* xr = (const float4*)&ctx[n2 * 128];
        const float4* wk = (const float4*)(Wi + (size_t)(128 + e) * 128);
        const float4* wv = (const float4*)(Wi + (size_t)(256 + e) * 128);
        float acck = bi[128 + e], accv = bi[256 + e];
        #pragma unroll 8
        for (int j = 0; j < 32; ++j) {
            const float4 a = xr[j];
            acck += dot4_(a, wk[j]); accv += dot4_(a, wv[j]);
        }
        ksh[n2 * 128 + e] = acck; vsh[n2 * 128 + e] = accv;
    }
    __syncthreads();
    if (tid < 4) {
        const int h = tid;
        float s[4]; float m = -1e30f;
        for (int n2 = 0; n2 < nc; ++n2) {
            float acc = 0.f;
            #pragma unroll
            for (int d = 0; d < 32; ++d) acc += qsh[h*32 + d] * ksh[n2*128 + h*32 + d];
            s[n2] = acc * 0.17677669529663687f;
            m = fmaxf(m, s[n2]);
        }
        float ssum = 0.f;
        for (int n2 = 0; n2 < nc; ++n2) { s[n2] = __expf(s[n2] - m); ssum += s[n2]; }
        const float inv = 1.f / ssum;
        for (int n2 = 0; n2 < nc; ++n2) att2[h*4 + n2] = s[n2] * inv;
    }
    __syncthreads();
    {
        const int h = e >> 5;
        float oacc = 0.f;
        for (int n2 = 0; n2 < nc; ++n2) oacc += att2[h*4 + n2] * vsh[n2*128 + e];
        osh[e] = oacc;
    }
    __syncthreads();
    float res;
    {
        const float4* wr = (const float4*)(ca_out_w + (size_t)ci*128*128 + (size_t)e*128);
        const float4* orow = (const float4*)osh;
        float acc = ca_out_b[ci*128 + e];
        #pragma unroll 8
        for (int j = 0; j < 32; ++j) acc += dot4_(orow[j], wr[j]);
        res = acc + cen[e];
    }
    const int lane = tid & 63, wid = tid >> 6;
    float sum = res;
    #pragma unroll
    for (int off = 32; off > 0; off >>= 1) sum += __shfl_down(sum, off, 64);
    if (lane == 0) red[wid] = sum;
    __syncthreads();
    const float mean = (red[0] + red[1]) * (1.f / 128.f);
    const float dv = res - mean;
    __syncthreads();
    float s2 = dv * dv;
    #pragma unroll
    for (int off = 32; off > 0; off >>= 1) s2 += __shfl_down(s2, off, 64);
    if (lane == 0) red[wid] = s2;
    __syncthreads();
    const float var = (red[0] + red[1]) * (1.f / 128.f);
    const float y = dv * rsqrtf(var + 1e-5f) * ln_g[ci*128 + e] + ln_b[ci*128 + e];
    seq[((size_t)bb * 64 + ci) * 128 + e] = y;
}

extern "C" void kernel_launch(void* const* d_in, const int* in_sizes, int n_in,
                              void* d_out, int out_size, void* d_ws, size_t ws_size,
                              hipStream_t stream) {
    const float* x        = (const float*)d_in[0];
    const float* w_ih_f   = (const float*)d_in[1];
    const float* w_hh_f   = (const float*)d_in[2];
    const float* b_ih_f   = (const float*)d_in[3];
    const float* b_hh_f   = (const float*)d_in[4];
    const float* w_ih_b   = (const float*)d_in[5];
    const float* w_hh_b   = (const float*)d_in[6];
    const float* b_ih_b   = (const float*)d_in[7];
    const float* b_hh_b   = (const float*)d_in[8];
    const float* sa_in_w  = (const float*)d_in[9];
    const float* sa_in_b  = (const float*)d_in[10];
    const float* sa_out_w = (const float*)d_in[11];
    const float* sa_out_b = (const float*)d_in[12];
    const float* proj_w   = (const float*)d_in[13];
    const float* proj_b   = (const float*)d_in[14];
    const float* ca_in_w  = (const float*)d_in[15];
    const float* ca_in_b  = (const float*)d_in[16];
    const float* ca_out_w = (const float*)d_in[17];
    const float* ca_out_b = (const float*)d_in[18];
    const float* ln_g     = (const float*)d_in[19];
    const float* ln_b     = (const float*)d_in[20];
    const float* fd1_w    = (const float*)d_in[21];
    const float* fd1_b    = (const float*)d_in[22];
    const float* fd2_w    = (const float*)d_in[23];
    const float* fd2_b    = (const float*)d_in[24];

    float* pooled = (float*)d_ws;
    float* seq    = pooled + 2097152;
    float* outp   = (float*)d_out;
    // head partials overlay the pooled region (dead after cross kernel reads it)
    float* part   = pooled;            // 8*256*64 floats = 512 KB

    const size_t base = 2ull * 8388608 + 8634368;
    const size_t loFull = 134217728ull;

    if (ws_size >= base + loFull / 4) {
        unsigned short* wbf = (unsigned short*)((char*)d_ws + 16777216);
        unsigned short* lo  = (unsigned short*)((char*)d_ws + base);
        unsigned short* w2bf = (unsigned short*)seq;          // 32 KB (dead by cross)
        float* b2f = (float*)(w2bf + 16384);
        const int npass = (ws_size >= base + loFull) ? 1
                        : (ws_size >= base + loFull / 2) ? 2 : 4;
        prep_weights<<<dim3(2048), dim3(256), 0, stream>>>(
            sa_in_w, sa_out_w, proj_w, w_ih_f, w_ih_b, w_hh_f, w_hh_b,
            ca_in_w, ca_out_w, wbf, NBF_FULL);
        prep_w2<<<dim3(128), dim3(128), 0, stream>>>(
            sa_out_w, sa_out_b, proj_w, proj_b, w2bf, b2f);
        const int chunk = 16384 / npass;
        for (int p = 0; p < npass; ++p) {
            const int win0 = p * chunk;
            lstm_kernel<<<dim3(chunk / 32), dim3(512), 0, stream>>>(
                x, b_ih_f, b_hh_f, b_ih_b, b_hh_b, wbf, lo, win0);
            attn_kernel<<<dim3(chunk), dim3(512), 0, stream>>>(
                wbf, sa_in_b, w2bf, b2f, lo, pooled, win0);
        }
        cross_mfma_kernel<<<dim3(1024), dim3(256), 0, stream>>>(
            pooled, wbf, ca_in_b, ca_out_b, ln_g, ln_b, seq);
    } else {
        unsigned short* wbf = (unsigned short*)seq;
        prep_weights<<<dim3(2048), dim3(256), 0, stream>>>(
            sa_in_w, sa_out_w, proj_w, w_ih_f, w_ih_b, w_hh_f, w_hh_b,
            ca_in_w, ca_out_w, wbf, NBF_SMALL);
        fused_window_kernel<<<dim3(16384), dim3(512), 0, stream>>>(
            x, w_ih_f, w_hh_f, b_ih_f, b_hh_f, w_ih_b, w_hh_b, b_ih_b, b_hh_b,
            sa_in_b, sa_out_b, proj_b, wbf, pooled);
        cross_attn_kernel<<<dim3(16384), dim3(128), 0, stream>>>(
            pooled, ca_in_w, ca_in_b, ca_out_w, ca_out_b, ln_g, ln_b, seq);
    }

    head1_kernel<<<dim3(512), dim3(256), 0, stream>>>(seq, fd1_w, part);
    head2_kernel<<<dim3(256), dim3(64), 0, stream>>>(part, fd1_b, fd2_w, fd2_b, outp);
}

// Round 11
// 594.964 us; speedup vs baseline: 1.4067x; 1.0082x over previous
//
#include <hip/hip_runtime.h>

// Problem constants: B=256, NW=64, WIN=32, FEAT=16, H=64, E=128, NH=4

typedef __attribute__((ext_vector_type(8))) short bf16x8;
typedef __attribute__((ext_vector_type(4))) float f32x4;

__device__ __forceinline__ unsigned short f2bf(float f) {
    union { float f; unsigned int u; } v; v.f = f;
    unsigned int u = v.u;
    return (unsigned short)((u + 0x7FFFu + ((u >> 16) & 1u)) >> 16);
}
__device__ __forceinline__ float dot4_(float4 a, float4 b) {
    return a.x*b.x + a.y*b.y + a.z*b.z + a.w*b.w;
}
__device__ __forceinline__ bf16x8 f2bf8(float4 a, float4 b) {
    bf16x8 o;
    o[0] = (short)f2bf(a.x); o[1] = (short)f2bf(a.y);
    o[2] = (short)f2bf(a.z); o[3] = (short)f2bf(a.w);
    o[4] = (short)f2bf(b.x); o[5] = (short)f2bf(b.y);
    o[6] = (short)f2bf(b.z); o[7] = (short)f2bf(b.w);
    return o;
}
__device__ __forceinline__ float bflo(unsigned u){ union{unsigned u;float f;}v; v.u=u<<16; return v.f; }
__device__ __forceinline__ float bfhi(unsigned u){ union{unsigned u;float f;}v; v.u=u&0xffff0000u; return v.f; }
// Pin a bf16 fragment in VGPRs (defeats loop rematerialization of the load).
#define KEEP(f) { uint4* _p = (uint4*)&(f); \
    asm volatile("" : "+v"(_p->x), "+v"(_p->y), "+v"(_p->z), "+v"(_p->w)); }

// bf16 weight arena layout (ushort element offsets)
#define W_SA_IN   0          // 49152  [384][128]
#define W_SA_OUT  49152      // 16384  [128][128]
#define W_PROJ    65536      // 16384  [128][128]
#define W_IH_F    81920      // 4096   [256][16]
#define W_IH_B    86016      // 4096
#define W_HH_F    90112      // 16384  [256][64]
#define W_HH_B    106496     // 16384
#define W_CA_IN   122880     // 64*49152 = 3145728
#define W_CA_OUT  3268608    // 64*16384 = 1048576
#define NBF_SMALL 122880
#define NBF_FULL  4317184

// ---------------- Kernel 0: weight prep (fp32 -> bf16) ----------------
__global__ __launch_bounds__(256)
void prep_weights(const float* __restrict__ sa_in_w, const float* __restrict__ sa_out_w,
                  const float* __restrict__ proj_w,
                  const float* __restrict__ w_ih_f, const float* __restrict__ w_ih_b,
                  const float* __restrict__ w_hh_f, const float* __restrict__ w_hh_b,
                  const float* __restrict__ ca_in_w, const float* __restrict__ ca_out_w,
                  unsigned short* __restrict__ wbf, int n)
{
    for (int i = blockIdx.x * 256 + threadIdx.x; i < n; i += gridDim.x * 256) {
        float v;
        if (i < W_SA_OUT)       v = sa_in_w[i];
        else if (i < W_PROJ)    v = sa_out_w[i - W_SA_OUT];
        else if (i < W_IH_F)    v = proj_w[i - W_PROJ];
        else if (i < W_IH_B)    v = w_ih_f[i - W_IH_F];
        else if (i < W_HH_F)    v = w_ih_b[i - W_IH_B];
        else if (i < W_HH_B)    v = w_hh_f[i - W_HH_F];
        else if (i < W_CA_IN)   v = w_hh_b[i - W_HH_B];
        else if (i < W_CA_OUT)  v = ca_in_w[i - W_CA_IN];
        else                    v = ca_out_w[i - W_CA_OUT];
        wbf[i] = f2bf(v);
    }
}

// ---------------- Kernel 0b: W2 = proj_w @ sa_out_w, b2 (linear-phase fold) --
__global__ __launch_bounds__(128)
void prep_w2(const float* __restrict__ sa_out_w, const float* __restrict__ sa_out_b,
             const float* __restrict__ proj_w, const float* __restrict__ proj_b,
             unsigned short* __restrict__ w2bf, float* __restrict__ b2f)
{
    __shared__ float pw[128];
    const int e = blockIdx.x, j = threadIdx.x;
    pw[j] = proj_w[e * 128 + j];
    __syncthreads();
    float acc = 0.f;
    #pragma unroll 8
    for (int k = 0; k < 128; ++k) acc += pw[k] * sa_out_w[k * 128 + j];
    w2bf[e * 128 + j] = f2bf(acc);
    if (j == 0) {
        float b = proj_b[e];
        for (int k = 0; k < 128; ++k) b += pw[k] * sa_out_b[k];
        b2f[e] = b;
    }
}

// ---------------- Kernel A: batched MFMA BiLSTM ----------------
#define HB 0            // hbuf[2 buf][2 dir][32 win][72] shorts = 9216
#define XS 9216         // x bf16 [32 win][520]
#define LSTM_SM 25856

__global__ __launch_bounds__(512)
void lstm_kernel(const float* __restrict__ x,
    const float* __restrict__ b_ih_f, const float* __restrict__ b_hh_f,
    const float* __restrict__ b_ih_b, const float* __restrict__ b_hh_b,
    const unsigned short* __restrict__ wbf,
    unsigned short* __restrict__ lo, int win0)
{
    __shared__ __align__(16) unsigned short sm[LSTM_SM];
    const int tid = threadIdx.x;
    const int gbase = win0 + blockIdx.x * 32;
    const int bb = gbase >> 6;
    const int wi0 = gbase & 63;

    for (int i = tid; i < 9216; i += 512) sm[HB + i] = 0;
    #pragma unroll
    for (int i = 0; i < 2; ++i) {
        const int p = tid + i * 512;
        const int win = p >> 5, t = p & 31;
        const float4* src = (const float4*)(x + ((size_t)bb * 2048 + (wi0 + win) * 32 + t) * 16);
        const float4 v0 = src[0], v1 = src[1], v2 = src[2], v3 = src[3];
        *(bf16x8*)&sm[XS + win * 520 + t * 16]     = f2bf8(v0, v1);
        *(bf16x8*)&sm[XS + win * 520 + t * 16 + 8] = f2bf8(v2, v3);
    }
    __syncthreads();

    const int w = tid >> 6, lane = tid & 63;
    const int dir = w >> 2, wd = w & 3;
    const int quad = lane >> 4, n16 = lane & 15;
    const bf16x8 zf = {};

    const unsigned short* whh = wbf + (dir ? W_HH_B : W_HH_F);
    const unsigned short* wih = wbf + (dir ? W_IH_B : W_IH_F);
    const float* bi = dir ? b_ih_b : b_ih_f;
    const float* bh = dir ? b_hh_b : b_hh_f;

    bf16x8 wf[4][2], xf[4];
    float bias[4];
    #pragma unroll
    for (int j = 0; j < 4; ++j) {
        const int g = 64 * j + wd * 16 + n16;
        wf[j][0] = *(const bf16x8*)(whh + g * 64 + quad * 8);
        wf[j][1] = *(const bf16x8*)(whh + g * 64 + 32 + quad * 8);
        KEEP(wf[j][0]); KEEP(wf[j][1]);
        xf[j] = (quad < 2) ? *(const bf16x8*)(wih + g * 16 + quad * 8) : zf;
        KEEP(xf[j]);
        bias[j] = bi[g] + bh[g];
    }
    float c[2][4] = {};
    const size_t loB = (size_t)blockIdx.x * 32;

    for (int s = 0; s < 32; ++s) {
        const int t = dir ? (31 - s) : s;
        const int cur = s & 1, nxt = cur ^ 1;
        #pragma unroll
        for (int mt = 0; mt < 2; ++mt) {
            const int hb = HB + ((cur * 2 + dir) * 32 + mt * 16 + n16) * 72;
            const bf16x8 ah0 = *(const bf16x8*)&sm[hb + quad * 8];
            const bf16x8 ah1 = *(const bf16x8*)&sm[hb + 32 + quad * 8];
            const bf16x8 ax = (quad < 2)
                ? *(const bf16x8*)&sm[XS + (mt * 16 + n16) * 520 + t * 16 + quad * 8] : zf;
            f32x4 ga[4];
            #pragma unroll
            for (int j = 0; j < 4; ++j) {
                f32x4 acc = {bias[j], bias[j], bias[j], bias[j]};
                acc = __builtin_amdgcn_mfma_f32_16x16x32_bf16(ah0, wf[j][0], acc, 0, 0, 0);
                acc = __builtin_amdgcn_mfma_f32_16x16x32_bf16(ah1, wf[j][1], acc, 0, 0, 0);
                acc = __builtin_amdgcn_mfma_f32_16x16x32_bf16(ax,  xf[j],   acc, 0, 0, 0);
                ga[j] = acc;
            }
            #pragma unroll
            for (int r = 0; r < 4; ++r) {
                const float iv = 1.f / (1.f + __expf(-ga[0][r]));
                const float fv = 1.f / (1.f + __expf(-ga[1][r]));
                const float gv = 2.f / (1.f + __expf(-2.f * ga[2][r])) - 1.f;
                const float ov = 1.f / (1.f + __expf(-ga[3][r]));
                c[mt][r] = fv * c[mt][r] + iv * gv;
                const float hv = ov * (2.f / (1.f + __expf(-2.f * c[mt][r])) - 1.f);
                sm[HB + ((nxt * 2 + dir) * 32 + mt * 16 + quad * 4 + r) * 72 + wd * 16 + n16]
                    = f2bf(hv);
            }
        }
        __syncthreads();
        {
            const int win = tid >> 4, part = tid & 15;
            const int d2 = part >> 3, u0 = (part & 7) * 8;
            const int t2 = d2 ? (31 - s) : s;
            const uint4 hv = *(const uint4*)&sm[HB + ((nxt * 2 + d2) * 32 + win) * 72 + u0];
            *(uint4*)(lo + ((loB + win) * 32 + t2) * 128 + d2 * 64 + u0) = hv;
        }
    }
}

// ---------------- Kernel B: per-window attention (MFMA, W2-folded) ----------
// Round-11: all global operands (QKV B-frags, biases, GEMV W2 row) prefetched
// into registers at kernel entry so their L2 latency overlaps the lo staging —
// round-10 post-mortem: ~9.5 us/block wall vs ~1.5 us issue = L2-latency-bound.
#define LO16 0        // lo[32][136]        (later osum[2][128] fp32)
#define Q16  4352     // q[32][136]         (later P, unnormalized)
#define K16  8704     // k[32][136]
#define VT16 13056    // vT[128][40]
#define SM16_TOTAL 18176

__global__ __launch_bounds__(512)
void attn_kernel(const unsigned short* __restrict__ wbf,
    const float* __restrict__ sa_in_b,
    const unsigned short* __restrict__ w2bf, const float* __restrict__ b2f,
    const unsigned short* __restrict__ lo,
    float* __restrict__ pooled, int win0)
{
    __shared__ __align__(16) unsigned short sm16[SM16_TOTAL];
    const int tid = threadIdx.x;
    const int w    = tid >> 6;
    const int lane = tid & 63;
    const int quad = lane >> 4;
    const int m16  = lane & 15;
    const unsigned short* wqkv = wbf + W_SA_IN;
    const f32x4 z = {0.f, 0.f, 0.f, 0.f};

    // ---- prefetch ALL global operands (independent of LDS; 17 loads in flight
    //      concurrently with the lo staging load below) ----
    bf16x8 bfr[3][4];
    float bias[3];
    #pragma unroll
    for (int i = 0; i < 3; ++i) {
        const int e = (w + i * 8) * 16 + m16;
        #pragma unroll
        for (int kk = 0; kk < 4; ++kk)
            bfr[i][kk] = *(const bf16x8*)(wqkv + (size_t)e*128 + kk*32 + quad*8);
        bias[i] = sa_in_b[e];
    }
    const int ge = tid >> 2, gpart = tid & 3;
    uint4 wg[4];
    #pragma unroll
    for (int j = 0; j < 4; ++j)
        wg[j] = *(const uint4*)(w2bf + ge * 128 + gpart * 32 + j * 8);
    const float gb = b2f[ge];

    // stage lo tile
    {
        const uint4 v = *(const uint4*)(lo + (size_t)blockIdx.x * 4096 + tid * 8);
        const int t = tid >> 4, e0 = (tid & 15) * 8;
        *(uint4*)&sm16[LO16 + t * 136 + e0] = v;
    }
    __syncthreads();   // (1)

    // ---- QKV: wave w owns nt = {w, w+8, w+16} -> i=0 all-q, i=1 all-k, i=2 all-v
    {
        bf16x8 afr[2][4];
        #pragma unroll
        for (int mt = 0; mt < 2; ++mt)
            #pragma unroll
            for (int kk = 0; kk < 4; ++kk)
                afr[mt][kk] = *(const bf16x8*)&sm16[LO16 + (mt*16 + m16)*136 + kk*32 + quad*8];
        #pragma unroll
        for (int i = 0; i < 3; ++i) {
            const int nt = w + i * 8;          // 0..7 q, 8..15 k, 16..23 v
            const int e = nt * 16 + m16;       // 0..383
            f32x4 acc0 = z, acc1 = z;
            #pragma unroll
            for (int kk = 0; kk < 4; ++kk) {
                acc0 = __builtin_amdgcn_mfma_f32_16x16x32_bf16(afr[0][kk], bfr[i][kk], acc0, 0, 0, 0);
                acc1 = __builtin_amdgcn_mfma_f32_16x16x32_bf16(afr[1][kk], bfr[i][kk], acc1, 0, 0, 0);
            }
            if (i == 0) {
                #pragma unroll
                for (int r = 0; r < 4; ++r) {
                    const int r0 = quad*4 + r;
                    sm16[Q16 + r0*136 + e]        = f2bf(acc0[r] + bias[0]);
                    sm16[Q16 + (16 + r0)*136 + e] = f2bf(acc1[r] + bias[0]);
                }
            } else if (i == 1) {
                const int ek = e - 128;
                #pragma unroll
                for (int r = 0; r < 4; ++r) {
                    const int r0 = quad*4 + r;
                    sm16[K16 + r0*136 + ek]        = f2bf(acc0[r] + bias[1]);
                    sm16[K16 + (16 + r0)*136 + ek] = f2bf(acc1[r] + bias[1]);
                }
            } else {
                const int ev = e - 256;
                #pragma unroll
                for (int r = 0; r < 4; ++r) {
                    const int r0 = quad*4 + r;
                    sm16[VT16 + ev*40 + r0]      = f2bf(acc0[r] + bias[2]);
                    sm16[VT16 + ev*40 + 16 + r0] = f2bf(acc1[r] + bias[2]);
                }
            }
        }
    }
    __syncthreads();   // (2) q,k,vT visible; lo (LO16) now dead

    // ---- scores + MFMA-softmax + P.V + t-sum of O (never materialize O) ----
    {
        const int h  = w >> 1;
        const int mt = w & 1;
        const bf16x8 aq  = *(const bf16x8*)&sm16[Q16 + (mt*16 + m16)*136 + h*32 + quad*8];
        const bf16x8 bk0 = *(const bf16x8*)&sm16[K16 + (m16)*136      + h*32 + quad*8];
        const bf16x8 bk1 = *(const bf16x8*)&sm16[K16 + (16 + m16)*136 + h*32 + quad*8];
        f32x4 s0 = __builtin_amdgcn_mfma_f32_16x16x32_bf16(aq, bk0, z, 0, 0, 0);
        f32x4 s1 = __builtin_amdgcn_mfma_f32_16x16x32_bf16(aq, bk1, z, 0, 0, 0);
        const float scale = 0.17677669529663687f;   // 1/sqrt(32)
        #pragma unroll
        for (int r = 0; r < 4; ++r) {
            const int rowt = mt*16 + quad*4 + r;
            sm16[Q16 + rowt*136 + h*32 + m16]      = f2bf(__expf(s0[r] * scale));
            sm16[Q16 + rowt*136 + h*32 + 16 + m16] = f2bf(__expf(s1[r] * scale));
        }
        const bf16x8 ap  = *(const bf16x8*)&sm16[Q16 + (mt*16 + m16)*136 + h*32 + quad*8];
        bf16x8 ones;
        #pragma unroll
        for (int j = 0; j < 8; ++j) ones[j] = (short)0x3F80;   // bf16 1.0
        const f32x4 sums = __builtin_amdgcn_mfma_f32_16x16x32_bf16(ap, ones, z, 0, 0, 0);
        const bf16x8 bv0 = *(const bf16x8*)&sm16[VT16 + (h*32 + m16)*40      + quad*8];
        const bf16x8 bv1 = *(const bf16x8*)&sm16[VT16 + (h*32 + 16 + m16)*40 + quad*8];
        f32x4 o0 = __builtin_amdgcn_mfma_f32_16x16x32_bf16(ap, bv0, z, 0, 0, 0);
        f32x4 o1 = __builtin_amdgcn_mfma_f32_16x16x32_bf16(ap, bv1, z, 0, 0, 0);
        float cs0 = 0.f, cs1 = 0.f;
        #pragma unroll
        for (int r = 0; r < 4; ++r) {
            const float inv = 1.f / sums[r];
            cs0 += o0[r] * inv;
            cs1 += o1[r] * inv;
        }
        cs0 += __shfl_xor(cs0, 16, 64); cs0 += __shfl_xor(cs0, 32, 64);
        cs1 += __shfl_xor(cs1, 16, 64); cs1 += __shfl_xor(cs1, 32, 64);
        float* osum = (float*)&sm16[LO16];   // [2 mt][128]
        if (quad == 0) {
            osum[mt*128 + h*32 + m16]      = cs0;
            osum[mt*128 + h*32 + 16 + m16] = cs1;
        }
    }
    __syncthreads();   // (3) osum visible

    // ---- GEMV: pooled = mean_t(O) @ W2^T + b2  (prefetched W2 row) ----
    {
        const float* osum = (const float*)&sm16[LO16];
        const int k0 = gpart * 32;
        float acc = 0.f;
        #pragma unroll
        for (int j = 0; j < 4; ++j) {
            const int kk = k0 + j * 8;
            const float4 a0 = *(const float4*)&osum[kk];
            const float4 a1 = *(const float4*)&osum[kk + 4];
            const float4 b0 = *(const float4*)&osum[128 + kk];
            const float4 b1 = *(const float4*)&osum[128 + kk + 4];
            const uint4 u = wg[j];
            acc += (a0.x + b0.x) * bflo(u.x);
            acc += (a0.y + b0.y) * bfhi(u.x);
            acc += (a0.z + b0.z) * bflo(u.y);
            acc += (a0.w + b0.w) * bfhi(u.y);
            acc += (a1.x + b1.x) * bflo(u.z);
            acc += (a1.y + b1.y) * bfhi(u.z);
            acc += (a1.z + b1.z) * bflo(u.w);
            acc += (a1.w + b1.w) * bfhi(u.w);
        }
        acc += __shfl_xor(acc, 1, 64);
        acc += __shfl_xor(acc, 2, 64);
        if (gpart == 0)
            pooled[((size_t)(win0 + blockIdx.x)) * 128 + ge] = acc * 0.03125f + gb;
    }
}

// ---------------- Kernel C: cross-attention + LN (MFMA, 16 batch rows/block) --
__global__ __launch_bounds__(256)
void cross_mfma_kernel(const float* __restrict__ pooled,
    const unsigned short* __restrict__ wbf,
    const float* __restrict__ ca_in_b, const float* __restrict__ ca_out_b,
    const float* __restrict__ ln_g, const float* __restrict__ ln_b,
    float* __restrict__ seq)
{
    __shared__ __align__(16) float cenf[16 * 128];
    __shared__ __align__(16) unsigned short cenb[16 * 136];
    __shared__ __align__(16) unsigned short ctxb[64 * 136];
    __shared__ __align__(16) unsigned short qb[16 * 136];
    __shared__ __align__(16) unsigned short kb[64 * 136];
    __shared__ __align__(16) unsigned short ob[16 * 136];
    __shared__ float attr[256];
    __shared__ float att[256];

    const int blk = blockIdx.x;
    const int ci = blk >> 4;
    const int ch = blk & 15;
    const int tid = threadIdx.x;
    const int w = tid >> 6, lane = tid & 63, quad = lane >> 4, n16 = lane & 15;

    const int left  = (ci - 2 > 0) ? ci - 2 : 0;
    const int right = (ci + 3 < 64) ? ci + 3 : 64;
    const int nc = right - left - 1;

    {
        const int b = tid >> 4, e0 = (tid & 15) * 8;
        const float4* src = (const float4*)(pooled + ((size_t)(ch*16 + b)*64 + ci)*128 + e0);
        const float4 v0 = src[0], v1 = src[1];
        *(float4*)&cenf[b*128 + e0]     = v0;
        *(float4*)&cenf[b*128 + e0 + 4] = v1;
        *(bf16x8*)&cenb[b*136 + e0] = f2bf8(v0, v1);
        for (int n2 = 0; n2 < nc; ++n2) {
            int idx = left + n2; if (idx >= ci) idx++;
            const float4* s2 = (const float4*)(pooled + ((size_t)(ch*16 + b)*64 + idx)*128 + e0);
            *(bf16x8*)&ctxb[(n2*16 + b)*136 + e0] = f2bf8(s2[0], s2[1]);
        }
    }
    __syncthreads();

    const unsigned short* wi = wbf + W_CA_IN + (size_t)ci * 49152;

    #pragma unroll
    for (int i = 0; i < 2; ++i) {
        const int nt = w + i * 4;
        const int e = nt * 16 + n16;
        {
            const float bq = ca_in_b[ci*384 + e];
            f32x4 acc = {bq, bq, bq, bq};
            #pragma unroll
            for (int kk = 0; kk < 4; ++kk) {
                const bf16x8 a = *(const bf16x8*)&cenb[n16*136 + kk*32 + quad*8];
                const bf16x8 bfr = *(const bf16x8*)(wi + (size_t)e*128 + kk*32 + quad*8);
                acc = __builtin_amdgcn_mfma_f32_16x16x32_bf16(a, bfr, acc, 0, 0, 0);
            }
            #pragma unroll
            for (int r = 0; r < 4; ++r) qb[(quad*4 + r)*136 + e] = f2bf(acc[r]);
        }
        {
            bf16x8 bk[4];
            #pragma unroll
            for (int kk = 0; kk < 4; ++kk)
                bk[kk] = *(const bf16x8*)(wi + (size_t)(128 + e)*128 + kk*32 + quad*8);
            const float bkb = ca_in_b[ci*384 + 128 + e];
            for (int mt = 0; mt < nc; ++mt) {
                f32x4 acc = {bkb, bkb, bkb, bkb};
                #pragma unroll
                for (int kk = 0; kk < 4; ++kk) {
                    const bf16x8 a = *(const bf16x8*)&ctxb[(mt*16 + n16)*136 + kk*32 + quad*8];
                    acc = __builtin_amdgcn_mfma_f32_16x16x32_bf16(a, bk[kk], acc, 0, 0, 0);
                }
                #pragma unroll
                for (int r = 0; r < 4; ++r) kb[(mt*16 + quad*4 + r)*136 + e] = f2bf(acc[r]);
            }
        }
    }
    __syncthreads();

    {
        const int h = w;
        const bf16x8 aq = *(const bf16x8*)&qb[n16*136 + h*32 + quad*8];
        for (int n2 = 0; n2 < nc; ++n2) {
            const bf16x8 bk = *(const bf16x8*)&kb[(n2*16 + n16)*136 + h*32 + quad*8];
            const f32x4 z = {0.f, 0.f, 0.f, 0.f};
            const f32x4 s = __builtin_amdgcn_mfma_f32_16x16x32_bf16(aq, bk, z, 0, 0, 0);
            if ((n16 >> 2) == quad)
                attr[(h*4 + n2)*16 + n16] = s[n16 & 3] * 0.17677669529663687f;
        }
    }
    __syncthreads();

    if (tid < 64) {
        const int b = tid & 15, h = tid >> 4;
        float m = -1e30f;
        for (int n2 = 0; n2 < nc; ++n2) m = fmaxf(m, attr[(h*4 + n2)*16 + b]);
        float e2[4]; float sum = 0.f;
        for (int n2 = 0; n2 < nc; ++n2) { e2[n2] = __expf(attr[(h*4 + n2)*16 + b] - m); sum += e2[n2]; }
        const float inv = 1.f / sum;
        for (int n2 = 0; n2 < nc; ++n2) att[b*16 + h*4 + n2] = e2[n2] * inv;
    }
    __syncthreads();

    #pragma unroll
    for (int i = 0; i < 2; ++i) {
        const int nt = w + i * 4;
        const int e = nt * 16 + n16;
        const int he = nt >> 1;
        bf16x8 bv[4];
        #pragma unroll
        for (int kk = 0; kk < 4; ++kk)
            bv[kk] = *(const bf16x8*)(wi + (size_t)(256 + e)*128 + kk*32 + quad*8);
        const float bvb = ca_in_b[ci*384 + 256 + e];
        float accO[4] = {bvb, bvb, bvb, bvb};
        for (int mt = 0; mt < nc; ++mt) {
            f32x4 vv = {0.f, 0.f, 0.f, 0.f};
            #pragma unroll
            for (int kk = 0; kk < 4; ++kk) {
                const bf16x8 a = *(const bf16x8*)&ctxb[(mt*16 + n16)*136 + kk*32 + quad*8];
                vv = __builtin_amdgcn_mfma_f32_16x16x32_bf16(a, bv[kk], vv, 0, 0, 0);
            }
            #pragma unroll
            for (int r = 0; r < 4; ++r)
                accO[r] += att[(quad*4 + r)*16 + he*4 + mt] * vv[r];
        }
        #pragma unroll
        for (int r = 0; r < 4; ++r) ob[(quad*4 + r)*136 + e] = f2bf(accO[r]);
    }
    __syncthreads();

    const unsigned short* wo = wbf + W_CA_OUT + (size_t)ci * 16384;
    float* resf = (float*)ctxb;
    #pragma unroll
    for (int i = 0; i < 2; ++i) {
        const int nt = w + i * 4;
        const int e = nt * 16 + n16;
        const float bo = ca_out_b[ci*128 + e];
        f32x4 acc = {bo, bo, bo, bo};
        #pragma unroll
        for (int kk = 0; kk < 4; ++kk) {
            const bf16x8 a = *(const bf16x8*)&ob[n16*136 + kk*32 + quad*8];
            const bf16x8 bfr = *(const bf16x8*)(wo + (size_t)e*128 + kk*32 + quad*8);
            acc = __builtin_amdgcn_mfma_f32_16x16x32_bf16(a, bfr, acc, 0, 0, 0);
        }
        #pragma unroll
        for (int r = 0; r < 4; ++r) {
            const int b2 = quad*4 + r;
            resf[b2*128 + e] = acc[r] + cenf[b2*128 + e];
        }
    }
    __syncthreads();

    {
        const int b = tid >> 4, i16 = tid & 15;
        const float4 v0 = *(float4*)&resf[b*128 + i16*8];
        const float4 v1 = *(float4*)&resf[b*128 + i16*8 + 4];
        float sum = v0.x+v0.y+v0.z+v0.w + v1.x+v1.y+v1.z+v1.w;
        float sq = v0.x*v0.x+v0.y*v0.y+v0.z*v0.z+v0.w*v0.w
                 + v1.x*v1.x+v1.y*v1.y+v1.z*v1.z+v1.w*v1.w;
        #pragma unroll
        for (int msk = 1; msk < 16; msk <<= 1) {
            sum += __shfl_xor(sum, msk, 64);
            sq  += __shfl_xor(sq, msk, 64);
        }
        const float mean = sum * (1.f / 128.f);
        const float var = sq * (1.f / 128.f) - mean * mean;
        const float rstd = rsqrtf(var + 1e-5f);
        float* dst = seq + ((size_t)(ch*16 + b)*64 + ci)*128 + i16*8;
        const float* gp = ln_g + ci*128 + i16*8;
        const float* bp = ln_b + ci*128 + i16*8;
        float4 o0, o1;
        o0.x = (v0.x-mean)*rstd*gp[0]+bp[0]; o0.y = (v0.y-mean)*rstd*gp[1]+bp[1];
        o0.z = (v0.z-mean)*rstd*gp[2]+bp[2]; o0.w = (v0.w-mean)*rstd*gp[3]+bp[3];
        o1.x = (v1.x-mean)*rstd*gp[4]+bp[4]; o1.y = (v1.y-mean)*rstd*gp[5]+bp[5];
        o1.z = (v1.z-mean)*rstd*gp[6]+bp[6]; o1.w = (v1.w-mean)*rstd*gp[7]+bp[7];
        *(float4*)dst = o0;
        *(float4*)(dst + 4) = o1;
    }
}

// ---------------- Head stage 1: partial z = seq @ fd1_w^T, k-split ----------
__global__ __launch_bounds__(256)
void head1_kernel(const float* __restrict__ seq, const float* __restrict__ fd1_w,
                  float* __restrict__ part)
{
    const int rg = blockIdx.x & 63;     // rows 4*rg .. 4*rg+3
    const int kq = blockIdx.x >> 6;     // 0..7, k-slice of 1024
    const int tid = threadIdx.x;
    const int j = tid & 63;             // unit
    const int sub = tid >> 6;           // 0..3, 256-k sub-slice
    const int k0 = kq * 1024 + sub * 256;
    __shared__ float4 red[256];
    float a0 = 0.f, a1 = 0.f, a2 = 0.f, a3 = 0.f;
    const float4* wr = (const float4*)(fd1_w + (size_t)j * 8192 + k0);
    const float4* s0 = (const float4*)(seq + ((size_t)rg*4 + 0) * 8192 + k0);
    const float4* s1 = (const float4*)(seq + ((size_t)rg*4 + 1) * 8192 + k0);
    const float4* s2 = (const float4*)(seq + ((size_t)rg*4 + 2) * 8192 + k0);
    const float4* s3 = (const float4*)(seq + ((size_t)rg*4 + 3) * 8192 + k0);
    #pragma unroll 4
    for (int i = 0; i < 64; ++i) {
        const float4 w4 = wr[i];
        a0 += dot4_(s0[i], w4);
        a1 += dot4_(s1[i], w4);
        a2 += dot4_(s2[i], w4);
        a3 += dot4_(s3[i], w4);
    }
    red[tid] = make_float4(a0, a1, a2, a3);
    __syncthreads();
    if (tid < 64) {
        const float4 v0 = red[tid], v1 = red[64 + tid], v2 = red[128 + tid], v3 = red[192 + tid];
        float4 t;
        t.x = v0.x + v1.x + v2.x + v3.x;
        t.y = v0.y + v1.y + v2.y + v3.y;
        t.z = v0.z + v1.z + v2.z + v3.z;
        t.w = v0.w + v1.w + v2.w + v3.w;
        float* pb = part + ((size_t)kq * 256 + rg * 4) * 64 + tid;
        pb[0]   = t.x;
        pb[64]  = t.y;
        pb[128] = t.z;
        pb[192] = t.w;
    }
}

// ---------------- Head stage 2: reduce + ReLU + 5-out GEMV ----------------
__global__ __launch_bounds__(64)
void head2_kernel(const float* __restrict__ part,
    const float* __restrict__ fd1_b,
    const float* __restrict__ fd2_w, const float* __restrict__ fd2_b,
    float* __restrict__ out)
{
    const int row = blockIdx.x;
    const int u = threadIdx.x;
    __shared__ float h1[64];
    float s = fd1_b[u];
    #pragma unroll
    for (int kq = 0; kq < 8; ++kq)
        s += part[((size_t)kq * 256 + row) * 64 + u];
    h1[u] = fmaxf(s, 0.f);
    __syncthreads();
    if (u < 5) {
        float acc = fd2_b[u];
        const float* w2 = fd2_w + u * 64;
        #pragma unroll
        for (int k = 0; k < 64; ++k) acc += h1[k] * w2[k];
        out[row * 5 + u] = acc;
    }
}

// =====================  FALLBACK PATH (round-4, known-good)  =================
__global__ __launch_bounds__(512)
void fused_window_kernel(const float* __restrict__ x,
    const float* __restrict__ w_ih_f, const float* __restrict__ w_hh_f,
    const float* __restrict__ b_ih_f, const float* __restrict__ b_hh_f,
    const float* __restrict__ w_ih_b, const float* __restrict__ w_hh_b,
    const float* __restrict__ b_ih_b, const float* __restrict__ b_hh_b,
    const float* __restrict__ sa_in_b, const float* __restrict__ sa_out_b,
    const float* __restrict__ proj_b,
    const unsigned short* __restrict__ wbf,
    float* __restrict__ pooled)
{
    __shared__ __align__(16) unsigned short sm16[SM16_TOTAL];
    float* xs   = (float*)&sm16[VT16];
    float* hbuf = xs + 512;
    const int tid = threadIdx.x;
    const int blk = blockIdx.x;
    const int bb = blk >> 6, wi2 = blk & 63;
    {
        const float* xsrc = x + ((size_t)bb * 2048 + wi2 * 32) * 16;
        xs[tid & 511] = xsrc[tid];
        if (tid < 256) hbuf[tid] = 0.f;
    }
    __syncthreads();
    {
        const int dir  = tid >> 8;
        const int gg   = tid & 255;
        const int u    = gg >> 2;
        const int gate = gg & 3;
        const int row  = gate * 64 + u;
        const float4* wih_p = (const float4*)((dir ? w_ih_b : w_ih_f) + row * 16);
        const float4* whh_p = (const float4*)((dir ? w_hh_b : w_hh_f) + row * 64);
        float4 wih[4];
        #pragma unroll
        for (int i = 0; i < 4; ++i) wih[i] = wih_p[i];
        float4 whh[16];
        #pragma unroll
        for (int i = 0; i < 16; ++i) whh[i] = whh_p[i];
        const float bias = dir ? (b_ih_b[row] + b_hh_b[row]) : (b_ih_f[row] + b_hh_f[row]);
        const float km  = (gate == 2) ? 2.f : 1.f;
        const float ofs = (gate == 2) ? -1.f : 0.f;
        const int qb2 = (tid & 63) & ~3;
        float c = 0.f;
        for (int step = 0; step < 32; ++step) {
            const int t = dir ? (31 - step) : step;
            const float4* h4 = (const float4*)&hbuf[(step & 1) * 128 + dir * 64];
            const float4* x4 = (const float4*)&xs[t * 16];
            float a0 = bias, a1 = 0.f, a2 = 0.f, a3 = 0.f;
            #pragma unroll
            for (int j = 0; j < 16; j += 4) {
                a0 += dot4_(h4[j], whh[j]);     a1 += dot4_(h4[j+1], whh[j+1]);
                a2 += dot4_(h4[j+2], whh[j+2]); a3 += dot4_(h4[j+3], whh[j+3]);
            }
            a0 += dot4_(x4[0], wih[0]); a1 += dot4_(x4[1], wih[1]);
            a2 += dot4_(x4[2], wih[2]); a3 += dot4_(x4[3], wih[3]);
            const float acc = (a0 + a1) + (a2 + a3);
            const float act = km / (1.f + __expf(-km * acc)) + ofs;
            const float iv = __shfl(act, qb2 + 0, 64);
            const float fv = __shfl(act, qb2 + 1, 64);
            const float gv = __shfl(act, qb2 + 2, 64);
            const float ov = __shfl(act, qb2 + 3, 64);
            c = fv * c + iv * gv;
            const float h = ov * (2.f / (1.f + __expf(-2.f * c)) - 1.f);
            if (gate == 0) {
                hbuf[((step + 1) & 1) * 128 + dir * 64 + u] = h;
                sm16[LO16 + t * 136 + dir * 64 + u] = f2bf(h);
            }
            __syncthreads();
        }
    }
    const int w = tid >> 6, lane = tid & 63, quad = lane >> 4, m16 = lane & 15;
    const unsigned short* wqkv = wbf + W_SA_IN;
    const unsigned short* wout = wbf + W_SA_OUT;
    const unsigned short* wprj = wbf + W_PROJ;
    {
        const int mt = w & 1, ng = w >> 1;
        bf16x8 afr[4];
        #pragma unroll
        for (int kk = 0; kk < 4; ++kk)
            afr[kk] = *(const bf16x8*)&sm16[LO16 + (mt*16 + m16)*136 + kk*32 + quad*8];
        #pragma unroll
        for (int i = 0; i < 6; ++i) {
            const int nt = ng * 6 + i;
            f32x4 acc = {0.f, 0.f, 0.f, 0.f};
            #pragma unroll
            for (int kk = 0; kk < 4; ++kk) {
                const bf16x8 bfr = *(const bf16x8*)(wqkv + (nt*16 + m16)*128 + kk*32 + quad*8);
                acc = __builtin_amdgcn_mfma_f32_16x16x32_bf16(afr[kk], bfr, acc, 0, 0, 0);
            }
            const int e = nt * 16 + m16;
            const float bias = sa_in_b[e];
            #pragma unroll
            for (int r = 0; r < 4; ++r) {
                const int rowt = mt*16 + quad*4 + r;
                const unsigned short hv = f2bf(acc[r] + bias);
                if (e < 128)       sm16[Q16 + rowt*136 + e] = hv;
                else if (e < 256)  sm16[K16 + rowt*136 + (e - 128)] = hv;
                else               sm16[VT16 + (e - 256)*40 + rowt] = hv;
            }
        }
    }
    __syncthreads();
    {
        const int h = w >> 1, mt = w & 1;
        const bf16x8 aq  = *(const bf16x8*)&sm16[Q16 + (mt*16 + m16)*136 + h*32 + quad*8];
        const bf16x8 bk0 = *(const bf16x8*)&sm16[K16 + (m16)*136      + h*32 + quad*8];
        const bf16x8 bk1 = *(const bf16x8*)&sm16[K16 + (16 + m16)*136 + h*32 + quad*8];
        __syncthreads();
        const f32x4 z = {0.f, 0.f, 0.f, 0.f};
        f32x4 s0 = __builtin_amdgcn_mfma_f32_16x16x32_bf16(aq, bk0, z, 0, 0, 0);
        f32x4 s1 = __builtin_amdgcn_mfma_f32_16x16x32_bf16(aq, bk1, z, 0, 0, 0);
        const float scale = 0.17677669529663687f;
        #pragma unroll
        for (int r = 0; r < 4; ++r) {
            float v0 = s0[r] * scale, v1 = s1[r] * scale;
            float mx = fmaxf(v0, v1);
            #pragma unroll
            for (int msk = 1; msk < 16; msk <<= 1) mx = fmaxf(mx, __shfl_xor(mx, msk, 64));
            const float e0 = __expf(v0 - mx), e1 = __expf(v1 - mx);
            float sum = e0 + e1;
            #pragma unroll
            for (int msk = 1; msk < 16; msk <<= 1) sum += __shfl_xor(sum, msk, 64);
            const float inv = 1.f / sum;
            const int rowt = mt*16 + quad*4 + r;
            sm16[Q16 + rowt*136 + h*32 + m16]      = f2bf(e0 * inv);
            sm16[Q16 + rowt*136 + h*32 + 16 + m16] = f2bf(e1 * inv);
        }
        const bf16x8 ap  = *(const bf16x8*)&sm16[Q16 + (mt*16 + m16)*136 + h*32 + quad*8];
        const bf16x8 bv0 = *(const bf16x8*)&sm16[VT16 + (h*32 + m16)*40      + quad*8];
        const bf16x8 bv1 = *(const bf16x8*)&sm16[VT16 + (h*32 + 16 + m16)*40 + quad*8];
        f32x4 o0 = __builtin_amdgcn_mfma_f32_16x16x32_bf16(ap, bv0, z, 0, 0, 0);
        f32x4 o1 = __builtin_amdgcn_mfma_f32_16x16x32_bf16(ap, bv1, z, 0, 0, 0);
        #pragma unroll
        for (int r = 0; r < 4; ++r) {
            const int rowt = mt*16 + quad*4 + r;
            sm16[K16 + rowt*136 + h*32 + m16]      = f2bf(o0[r]);
            sm16[K16 + rowt*136 + h*32 + 16 + m16] = f2bf(o1[r]);
        }
    }
    __syncthreads();
    {
        const int mt = w & 1;
        bf16x8 ao[4];
        #pragma unroll
        for (int kk = 0; kk < 4; ++kk)
            ao[kk] = *(const bf16x8*)&sm16[K16 + (mt*16 + m16)*136 + kk*32 + quad*8];
        #pragma unroll
        for (int i = 0; i < 2; ++i) {
            const int nt = (w >> 1) * 2 + i;
            f32x4 acc = {0.f, 0.f, 0.f, 0.f};
            #pragma unroll
            for (int kk = 0; kk < 4; ++kk) {
                const bf16x8 bfr = *(const bf16x8*)(wout + (nt*16 + m16)*128 + kk*32 + quad*8);
                acc = __builtin_amdgcn_mfma_f32_16x16x32_bf16(ao[kk], bfr, acc, 0, 0, 0);
            }
            const int e = nt * 16 + m16;
            const float bias = sa_out_b[e];
            #pragma unroll
            for (int r = 0; r < 4; ++r)
                sm16[LO16 + (mt*16 + quad*4 + r)*136 + e] = f2bf(acc[r] + bias);
        }
    }
    __syncthreads();
    {
        f32x4 acc0 = {0.f, 0.f, 0.f, 0.f};
        f32x4 acc1 = {0.f, 0.f, 0.f, 0.f};
        #pragma unroll
        for (int kk = 0; kk < 4; ++kk) {
            const bf16x8 a0 = *(const bf16x8*)&sm16[LO16 + (m16)*136      + kk*32 + quad*8];
            const bf16x8 a1 = *(const bf16x8*)&sm16[LO16 + (16 + m16)*136 + kk*32 + quad*8];
            const bf16x8 bfr = *(const bf16x8*)(wprj + (w*16 + m16)*128 + kk*32 + quad*8);
            acc0 = __builtin_amdgcn_mfma_f32_16x16x32_bf16(a0, bfr, acc0, 0, 0, 0);
            acc1 = __builtin_amdgcn_mfma_f32_16x16x32_bf16(a1, bfr, acc1, 0, 0, 0);
        }
        float s = (acc0[0] + acc0[1]) + (acc0[2] + acc0[3])
                + (acc1[0] + acc1[1]) + (acc1[2] + acc1[3]);
        s += __shfl_down(s, 32, 64);
        s += __shfl_down(s, 16, 64);
        if (lane < 16) {
            const int e = w * 16 + lane;
            pooled[(size_t)blk * 128 + e] = s * 0.03125f + proj_b[e];
        }
    }
}

__global__ __launch_bounds__(128)
void cross_attn_kernel(const float* __restrict__ pooled,
    const float* __restrict__ ca_in_w, const float* __restrict__ ca_in_b,
    const float* __restrict__ ca_out_w, const float* __restrict__ ca_out_b,
    const float* __restrict__ ln_g, const float* __restrict__ ln_b,
    float* __restrict__ seq)
{
    const int blk = blockIdx.x;
    const int ci = blk >> 8, bb = blk & 255;
    const int tid = threadIdx.x;
    __shared__ float cen[128], ctx[512], qsh[128], ksh[512], vsh[512], osh[128];
    __shared__ float att2[16], red[2];
    const int left  = (ci - 2 > 0) ? ci - 2 : 0;
    const int right = (ci + 3 < 64) ? ci + 3 : 64;
    const int nc = right - left - 1;
    cen[tid] = pooled[((size_t)bb * 64 + ci) * 128 + tid];
    for (int n2 = 0; n2 < nc; ++n2) {
        int idx = left + n2; if (idx >= ci) idx++;
        ctx[n2 * 128 + tid] = pooled[((size_t)bb * 64 + idx) * 128 + tid];
    }
    __syncthreads();
    const float* Wi = ca_in_w + (size_t)ci * 384 * 128;
    const float* bi = ca_in_b + ci * 384;
    const int e = tid;
    {
        const float4* wr = (const float4*)(Wi + (size_t)e * 128);
        const float4* cr = (const float4*)cen;
        float acc = bi[e];
        #pragma unroll 8
        for (int j = 0; j < 32; ++j) acc += dot4_(cr[j], wr[j]);
        qsh[e] = acc;
    }
    for (int n2 = 0; n2 < nc; ++n2) {
        const float4* xr = (const float4*)&ctx[n2 * 128];
        const float4* wk = (const float4*)(Wi + (size_t)(128 + e) * 128);
        const float4* wv = (const float4*)(Wi + (size_t)(256 + e) * 128);
        float acck = bi[128 + e], accv = bi[256 + e];
        #pragma unroll 8
        for (int j = 0; j < 32; ++j) {
            const float4 a = xr[j];
            acck += dot4_(a, wk[j]); accv += dot4_(a, wv[j]);
        }
        ksh[n2 * 128 + e] = acck; vsh[n2 * 128 + e] = accv;
    }
    __syncthreads();
    if (tid < 4) {
        const int h = tid;
        float s[4]; float m = -1e30f;
        for (int n2 = 0; n2 < nc; ++n2) {
            float acc = 0.f;
            #pragma unroll
            for (int d = 0; d < 32; ++d) acc += qsh[h*32 + d] * ksh[n2*128 + h*32 + d];
            s[n2] = acc * 0.17677669529663687f;
            m = fmaxf(m, s[n2]);
        }
        float ssum = 0.f;
        for (int n2 = 0; n2 < nc; ++n2) { s[n2] = __expf(s[n2] - m); ssum += s[n2]; }
        const float inv = 1.f / ssum;
        for (int n2 = 0; n2 < nc; ++n2) att2[h*4 + n2] = s[n2] * inv;
    }
    __syncthreads();
    {
        const int h = e >> 5;
        float oacc = 0.f;
        for (int n2 = 0; n2 < nc; ++n2) oacc += att2[h*4 + n2] * vsh[n2*128 + e];
        osh[e] = oacc;
    }
    __syncthreads();
    float res;
    {
        const float4* wr = (const float4*)(ca_out_w + (size_t)ci*128*128 + (size_t)e*128);
        const float4* orow = (const float4*)osh;
        float acc = ca_out_b[ci*128 + e];
        #pragma unroll 8
        for (int j = 0; j < 32; ++j) acc += dot4_(orow[j], wr[j]);
        res = acc + cen[e];
    }
    const int lane = tid & 63, wid = tid >> 6;
    float sum = res;
    #pragma unroll
    for (int off = 32; off > 0; off >>= 1) sum += __shfl_down(sum, off, 64);
    if (lane == 0) red[wid] = sum;
    __syncthreads();
    const float mean = (red[0] + red[1]) * (1.f / 128.f);
    const float dv = res - mean;
    __syncthreads();
    float s2 = dv * dv;
    #pragma unroll
    for (int off = 32; off > 0; off >>= 1) s2 += __shfl_down(s2, off, 64);
    if (lane == 0) red[wid] = s2;
    __syncthreads();
    const float var = (red[0] + red[1]) * (1.f / 128.f);
    const float y = dv * rsqrtf(var + 1e-5f) * ln_g[ci*128 + e] + ln_b[ci*128 + e];
    seq[((size_t)bb * 64 + ci) * 128 + e] = y;
}

extern "C" void kernel_launch(void* const* d_in, const int* in_sizes, int n_in,
                              void* d_out, int out_size, void* d_ws, size_t ws_size,
                              hipStream_t stream) {
    const float* x        = (const float*)d_in[0];
    const float* w_ih_f   = (const float*)d_in[1];
    const float* w_hh_f   = (const float*)d_in[2];
    const float* b_ih_f   = (const float*)d_in[3];
    const float* b_hh_f   = (const float*)d_in[4];
    const float* w_ih_b   = (const float*)d_in[5];
    const float* w_hh_b   = (const float*)d_in[6];
    const float* b_ih_b   = (const float*)d_in[7];
    const float* b_hh_b   = (const float*)d_in[8];
    const float* sa_in_w  = (const float*)d_in[9];
    const float* sa_in_b  = (const float*)d_in[10];
    const float* sa_out_w = (const float*)d_in[11];
    const float* sa_out_b = (const float*)d_in[12];
    const float* proj_w   = (const float*)d_in[13];
    const float* proj_b   = (const float*)d_in[14];
    const float* ca_in_w  = (const float*)d_in[15];
    const float* ca_in_b  = (const float*)d_in[16];
    const float* ca_out_w = (const float*)d_in[17];
    const float* ca_out_b = (const float*)d_in[18];
    const float* ln_g     = (const float*)d_in[19];
    const float* ln_b     = (const float*)d_in[20];
    const float* fd1_w    = (const float*)d_in[21];
    const float* fd1_b    = (const float*)d_in[22];
    const float* fd2_w    = (const float*)d_in[23];
    const float* fd2_b    = (const float*)d_in[24];

    float* pooled = (float*)d_ws;
    float* seq    = pooled + 2097152;
    float* outp   = (float*)d_out;
    float* part   = pooled;            // head partials overlay pooled (dead then)

    const size_t base = 2ull * 8388608 + 8634368;
    const size_t loFull = 134217728ull;

    if (ws_size >= base + loFull / 4) {
        unsigned short* wbf = (unsigned short*)((char*)d_ws + 16777216);
        unsigned short* lo  = (unsigned short*)((char*)d_ws + base);
        unsigned short* w2bf = (unsigned short*)seq;          // 32 KB (dead by cross)
        float* b2f = (float*)(w2bf + 16384);
        const int npass = (ws_size >= base + loFull) ? 1
                        : (ws_size >= base + loFull / 2) ? 2 : 4;
        prep_weights<<<dim3(2048), dim3(256), 0, stream>>>(
            sa_in_w, sa_out_w, proj_w, w_ih_f, w_ih_b, w_hh_f, w_hh_b,
            ca_in_w, ca_out_w, wbf, NBF_FULL);
        prep_w2<<<dim3(128), dim3(128), 0, stream>>>(
            sa_out_w, sa_out_b, proj_w, proj_b, w2bf, b2f);
        const int chunk = 16384 / npass;
        for (int p = 0; p < npass; ++p) {
            const int win0 = p * chunk;
            lstm_kernel<<<dim3(chunk / 32), dim3(512), 0, stream>>>(
                x, b_ih_f, b_hh_f, b_ih_b, b_hh_b, wbf, lo, win0);
            attn_kernel<<<dim3(chunk), dim3(512), 0, stream>>>(
                wbf, sa_in_b, w2bf, b2f, lo, pooled, win0);
        }
        cross_mfma_kernel<<<dim3(1024), dim3(256), 0, stream>>>(
            pooled, wbf, ca_in_b, ca_out_b, ln_g, ln_b, seq);
    } else {
        unsigned short* wbf = (unsigned short*)seq;
        prep_weights<<<dim3(2048), dim3(256), 0, stream>>>(
            sa_in_w, sa_out_w, proj_w, w_ih_f, w_ih_b, w_hh_f, w_hh_b,
            ca_in_w, ca_out_w, wbf, NBF_SMALL);
        fused_window_kernel<<<dim3(16384), dim3(512), 0, stream>>>(
            x, w_ih_f, w_hh_f, b_ih_f, b_hh_f, w_ih_b, w_hh_b, b_ih_b, b_hh_b,
            sa_in_b, sa_out_b, proj_b, wbf, pooled);
        cross_attn_kernel<<<dim3(16384), dim3(128), 0, stream>>>(
            pooled, ca_in_w, ca_in_b, ca_out_w, ca_out_b, ln_g, ln_b, seq);
    }

    head1_kernel<<<dim3(512), dim3(256), 0, stream>>>(seq, fd1_w, part);
    head2_kernel<<<dim3(256), dim3(64), 0, stream>>>(part, fd1_b, fd2_w, fd2_b, outp);
}